// Round 1
// baseline (2598.115 us; speedup 1.0000x reference)
//
#include <hip/hip_runtime.h>

// ---- geometry ----
#define GSZ 32
#define GP 34                    // padded (+1 halo each side)
#define GP2 (GP*GP)              // 1156
#define GP3 (GP*GP2)             // 39304
#define PX  (GP*GP3)             // 1336336 floats per padded channel
#define POFF (GP3+GP2+GP+1)      // offset of (0,0,0,0) inside padded channel
#define NPTS (1<<20)             // 32^4

// per-pass slot layout (floats)
#define OFF_XIN 0
#define OFF_A   ((size_t)PX)
#define OFF_B   ((size_t)11*PX)
#define OFF_OT  ((size_t)21*PX)
#define SPASS   ((size_t)21*PX + NPTS)   // 29,111,632 floats = 116.4 MB

// ---------------------------------------------------------------
// copy input (branch 0: identity, branch 1: (i,j,k,l)<-(k,l,i,j))
// into zero-padded xin
// ---------------------------------------------------------------
__global__ __launch_bounds__(256) void k_copy_in(const float* __restrict__ x,
                                                 float* __restrict__ ws, int p0) {
    int p = p0 + blockIdx.z;
    int b = p >> 1, br = p & 1;
    int gid = blockIdx.x * 256 + threadIdx.x;
    int l = gid & 31, k = (gid >> 5) & 31, j = (gid >> 10) & 31, i = gid >> 15;
    const float* xb = x + (size_t)b * NPTS;
    float v;
    if (br == 0) v = xb[gid];
    else         v = xb[(((k * 32 + l) * 32 + i) * 32) + j];
    float* xin = ws + (size_t)blockIdx.z * SPASS + OFF_XIN;
    xin[POFF + i * GP3 + j * GP2 + k * GP + l] = v;
}

// ---------------------------------------------------------------
// conv1: 1 -> 10 channels, padded in, padded out, ReLU
// block = (32,32) over (i,j); 256 threads = l(32) x k0(8); 4 k's per thread
// ---------------------------------------------------------------
__global__ __launch_bounds__(256) void k_conv1(const float* __restrict__ W1,
                                               const float* __restrict__ B1,
                                               float* ws, int p0) {
    int z = blockIdx.z;
    int i = blockIdx.x, j = blockIdx.y;
    int t = threadIdx.x;
    int l = t & 31, k0 = t >> 5;
    const float* xin = ws + (size_t)z * SPASS + OFF_XIN;
    float* bufA = ws + (size_t)z * SPASS + OFF_A;

    float acc[10][4];
#pragma unroll
    for (int co = 0; co < 10; ++co) {
        float bb = B1[co];
#pragma unroll
        for (int m = 0; m < 4; ++m) acc[co][m] = bb;
    }

    const float* base = xin + POFF + (size_t)(i - 1) * GP3 + (j - 1) * GP2
                        + (k0 - 1) * GP + (l - 1);
#pragma unroll 1
    for (int d1 = 0; d1 < 3; ++d1)
#pragma unroll 1
        for (int d2 = 0; d2 < 3; ++d2) {
            const float* bp = base + d1 * GP3 + d2 * GP2;
#pragma unroll
            for (int d3 = 0; d3 < 3; ++d3)
#pragma unroll
                for (int d4 = 0; d4 < 3; ++d4) {
                    float v[4];
#pragma unroll
                    for (int m = 0; m < 4; ++m) v[m] = bp[m * 8 * GP + d3 * GP + d4];
                    int tap = ((d1 * 3 + d2) * 3 + d3) * 3 + d4;
#pragma unroll
                    for (int co = 0; co < 10; ++co) {
                        float w = W1[co * 81 + tap];
#pragma unroll
                        for (int m = 0; m < 4; ++m) acc[co][m] = fmaf(v[m], w, acc[co][m]);
                    }
                }
        }

    float* ob = bufA + POFF + (size_t)i * GP3 + j * GP2 + k0 * GP + l;
#pragma unroll
    for (int co = 0; co < 10; ++co)
#pragma unroll
        for (int m = 0; m < 4; ++m)
            ob[(size_t)co * PX + m * 8 * GP] = fmaxf(acc[co][m], 0.f);
}

// ---------------------------------------------------------------
// conv2: 10 -> 10 channels, padded in (bufA), padded out (bufB), ReLU
// ---------------------------------------------------------------
__global__ __launch_bounds__(256) void k_conv2(const float* __restrict__ W2,
                                               const float* __restrict__ B2,
                                               float* ws, int p0) {
    int z = blockIdx.z;
    int i = blockIdx.x, j = blockIdx.y;
    int t = threadIdx.x;
    int l = t & 31, k0 = t >> 5;
    const float* bufA = ws + (size_t)z * SPASS + OFF_A;
    float* bufB = ws + (size_t)z * SPASS + OFF_B;

    float acc[10][4];
#pragma unroll
    for (int co = 0; co < 10; ++co) {
        float bb = B2[co];
#pragma unroll
        for (int m = 0; m < 4; ++m) acc[co][m] = bb;
    }

#pragma unroll 1
    for (int cin = 0; cin < 10; ++cin) {
        const float* cbase = bufA + (size_t)cin * PX + POFF + (size_t)(i - 1) * GP3
                             + (j - 1) * GP2 + (k0 - 1) * GP + (l - 1);
#pragma unroll 1
        for (int d1 = 0; d1 < 3; ++d1)
#pragma unroll 1
            for (int d2 = 0; d2 < 3; ++d2) {
                const float* bp = cbase + d1 * GP3 + d2 * GP2;
#pragma unroll
                for (int d3 = 0; d3 < 3; ++d3)
#pragma unroll
                    for (int d4 = 0; d4 < 3; ++d4) {
                        float v[4];
#pragma unroll
                        for (int m = 0; m < 4; ++m) v[m] = bp[m * 8 * GP + d3 * GP + d4];
                        int tap = ((d1 * 3 + d2) * 3 + d3) * 3 + d4;
#pragma unroll
                        for (int co = 0; co < 10; ++co) {
                            float w = W2[(co * 10 + cin) * 81 + tap];
#pragma unroll
                            for (int m = 0; m < 4; ++m) acc[co][m] = fmaf(v[m], w, acc[co][m]);
                        }
                    }
            }
    }

    float* ob = bufB + POFF + (size_t)i * GP3 + j * GP2 + k0 * GP + l;
#pragma unroll
    for (int co = 0; co < 10; ++co)
#pragma unroll
        for (int m = 0; m < 4; ++m)
            ob[(size_t)co * PX + m * 8 * GP] = fmaxf(acc[co][m], 0.f);
}

// ---------------------------------------------------------------
// conv3: 10 -> 1 channel, padded in (bufB), ReLU
// branch 0: store to d_out[b]; branch 1: store to out_t slot (natural layout)
// ---------------------------------------------------------------
__global__ __launch_bounds__(256) void k_conv3(const float* __restrict__ W3,
                                               const float* __restrict__ B3,
                                               float* ws, float* __restrict__ out,
                                               int p0) {
    int z = blockIdx.z;
    int p = p0 + z;
    int b = p >> 1, br = p & 1;
    int i = blockIdx.x, j = blockIdx.y;
    int t = threadIdx.x;
    int l = t & 31, k0 = t >> 5;
    const float* bufB = ws + (size_t)z * SPASS + OFF_B;

    float acc[4];
    float bb = B3[0];
#pragma unroll
    for (int m = 0; m < 4; ++m) acc[m] = bb;

#pragma unroll 1
    for (int cin = 0; cin < 10; ++cin) {
        const float* cbase = bufB + (size_t)cin * PX + POFF + (size_t)(i - 1) * GP3
                             + (j - 1) * GP2 + (k0 - 1) * GP + (l - 1);
#pragma unroll 1
        for (int d1 = 0; d1 < 3; ++d1)
#pragma unroll 1
            for (int d2 = 0; d2 < 3; ++d2) {
                const float* bp = cbase + d1 * GP3 + d2 * GP2;
#pragma unroll
                for (int d3 = 0; d3 < 3; ++d3)
#pragma unroll
                    for (int d4 = 0; d4 < 3; ++d4) {
                        int tap = ((d1 * 3 + d2) * 3 + d3) * 3 + d4;
                        float w = W3[cin * 81 + tap];
#pragma unroll
                        for (int m = 0; m < 4; ++m)
                            acc[m] = fmaf(bp[m * 8 * GP + d3 * GP + d4], w, acc[m]);
                    }
            }
    }

    float* dst = (br == 0) ? (out + (size_t)b * NPTS)
                           : (ws + (size_t)z * SPASS + OFF_OT);
#pragma unroll
    for (int m = 0; m < 4; ++m)
        dst[(size_t)i * 32768 + j * 1024 + (k0 + 8 * m) * 32 + l] = fmaxf(acc[m], 0.f);
}

// ---------------------------------------------------------------
// out[b] (as M[p][q], p=i*32+j, q=k*32+l) += out_t[q][p]
// ---------------------------------------------------------------
__global__ __launch_bounds__(256) void k_tadd(float* __restrict__ out,
                                              const float* __restrict__ ot) {
    __shared__ float tile[32][33];
    int tx = threadIdx.x, ty = threadIdx.y;   // (32,8)
    int P0 = blockIdx.x * 32, Q0 = blockIdx.y * 32;
#pragma unroll
    for (int r = 0; r < 4; ++r)
        tile[ty + 8 * r][tx] = ot[(size_t)(Q0 + ty + 8 * r) * 1024 + P0 + tx];
    __syncthreads();
#pragma unroll
    for (int r = 0; r < 4; ++r)
        out[(size_t)(P0 + ty + 8 * r) * 1024 + Q0 + tx] += tile[tx][ty + 8 * r];
}

// ---------------------------------------------------------------
extern "C" void kernel_launch(void* const* d_in, const int* in_sizes, int n_in,
                              void* d_out, int out_size, void* d_ws, size_t ws_size,
                              hipStream_t stream) {
    const float* x  = (const float*)d_in[0];
    const float* W1 = (const float*)d_in[1];
    const float* b1 = (const float*)d_in[2];
    const float* W2 = (const float*)d_in[3];
    const float* b2 = (const float*)d_in[4];
    const float* W3 = (const float*)d_in[5];
    const float* b3 = (const float*)d_in[6];
    float* out = (float*)d_out;
    float* ws  = (float*)d_ws;

    size_t slot_bytes = SPASS * sizeof(float);
    int Gn = (int)(ws_size / slot_bytes);
    if (Gn > 2) Gn = 2;
    if (Gn < 1) Gn = 1;

    size_t zb = (size_t)Gn * slot_bytes;
    if (zb > ws_size) zb = ws_size;
    hipMemsetAsync(d_ws, 0, zb, stream);   // zero halos once; interiors overwritten

    for (int p0 = 0; p0 < 8; p0 += Gn) {
        int g = 8 - p0 < Gn ? 8 - p0 : Gn;
        k_copy_in<<<dim3(4096, 1, g), 256, 0, stream>>>(x, ws, p0);
        k_conv1<<<dim3(32, 32, g), 256, 0, stream>>>(W1, b1, ws, p0);
        k_conv2<<<dim3(32, 32, g), 256, 0, stream>>>(W2, b2, ws, p0);
        k_conv3<<<dim3(32, 32, g), 256, 0, stream>>>(W3, b3, ws, out, p0);
        for (int p = p0; p < p0 + g; ++p)
            if (p & 1)
                k_tadd<<<dim3(32, 32), dim3(32, 8), 0, stream>>>(
                    out + (size_t)(p >> 1) * NPTS,
                    ws + (size_t)(p - p0) * SPASS + OFF_OT);
    }
}

// Round 2
// 2109.498 us; speedup vs baseline: 1.2316x; 1.2316x over previous
//
#include <hip/hip_runtime.h>

// ---- geometry ----
#define GSZ 32
#define GP 34                    // padded (+1 halo each side)
#define GP2 (GP*GP)              // 1156
#define GP3 (GP*GP2)             // 39304
#define PX  (GP*GP3)             // 1336336 floats per padded fp32 channel
#define POFF (GP3+GP2+GP+1)      // offset of (0,0,0,0) inside padded channel
#define NPTS (1<<20)             // 32^4

// X2: bf16 [34][34][34][32][16]  (i,j,k padded; l=32; cin padded to 16)
#define X2_FLOATS ((size_t)34*34*34*32*8)   // 10,061,824 float-equivalents

// per-pass slot layout (float units)
#define OFF_XIN ((size_t)0)
#define OFF_X2  ((size_t)PX)
#define OFF_B   (OFF_X2 + X2_FLOATS)          // fp32 padded 10-ch conv2 output
#define OFF_OT  (OFF_B + (size_t)10*PX)
#define SPASS   (OFF_OT + (size_t)NPTS)       // 25,810,096 floats = 103.2 MB

#define WSB_FLOATS 8192   // packed-B region at start of ws (27*64*4 u32 used)

typedef __attribute__((ext_vector_type(8)))  short bf16x8;
typedef __attribute__((ext_vector_type(16))) float f32x16;

__device__ __forceinline__ unsigned short f2bf(float f) {
    union { float f; unsigned u; } v; v.f = f;
    unsigned r = v.u + 0x7FFFu + ((v.u >> 16) & 1u);   // RNE
    return (unsigned short)(r >> 16);
}

// ---------------------------------------------------------------
// pack W2 into MFMA B-fragments: wsB[g3][lane][4] u32, g3=(d1*3+d2)*3+d3
// B[k=cin][n] with n = d4*10+co (n<30), zeros elsewhere
// ---------------------------------------------------------------
__global__ void k_bpack(const float* __restrict__ W2, unsigned* __restrict__ wsB) {
    int t = threadIdx.x;
    int lane = t & 63, j = t >> 6;           // j = u32 index 0..3
    int n = lane & 31, kh = lane >> 5;
    for (int g = 0; g < 27; ++g) {
        unsigned v = 0;
        for (int e = 0; e < 2; ++e) {
            int ii = 2 * j + e;
            int k = kh * 8 + ii;             // cin
            unsigned short h = 0;
            if (k < 10 && n < 30) {
                int co = n % 10, d4 = n / 10;
                h = f2bf(W2[(co * 10 + k) * 81 + g * 3 + d4]);
            }
            v |= (unsigned)h << (16 * e);
        }
        wsB[(g * 64 + lane) * 4 + j] = v;
    }
}

// ---------------------------------------------------------------
// copy input (branch 0: identity, branch 1: (i,j,k,l)<-(k,l,i,j))
// ---------------------------------------------------------------
__global__ __launch_bounds__(256) void k_copy_in(const float* __restrict__ x,
                                                 float* __restrict__ ws, int p0) {
    int p = p0 + blockIdx.z;
    int b = p >> 1, br = p & 1;
    int gid = blockIdx.x * 256 + threadIdx.x;
    int l = gid & 31, k = (gid >> 5) & 31, j = (gid >> 10) & 31, i = gid >> 15;
    const float* xb = x + (size_t)b * NPTS;
    float v;
    if (br == 0) v = xb[gid];
    else         v = xb[(((k * 32 + l) * 32 + i) * 32) + j];
    float* xin = ws + (size_t)blockIdx.z * SPASS + OFF_XIN;
    xin[POFF + i * GP3 + j * GP2 + k * GP + l] = v;
}

// ---------------------------------------------------------------
// conv1: 1 -> 10, fp32 padded in, bf16 X2 out [34][34][34][32][16], ReLU
// ---------------------------------------------------------------
__global__ __launch_bounds__(256) void k_conv1(const float* __restrict__ W1,
                                               const float* __restrict__ B1,
                                               float* ws, int p0) {
    int z = blockIdx.z;
    int i = blockIdx.x, j = blockIdx.y;
    int t = threadIdx.x;
    int l = t & 31, k0 = t >> 5;
    const float* xin = ws + (size_t)z * SPASS + OFF_XIN;

    float acc[10][4];
#pragma unroll
    for (int co = 0; co < 10; ++co) {
        float bb = B1[co];
#pragma unroll
        for (int m = 0; m < 4; ++m) acc[co][m] = bb;
    }

    const float* base = xin + POFF + (size_t)(i - 1) * GP3 + (j - 1) * GP2
                        + (k0 - 1) * GP + (l - 1);
#pragma unroll 1
    for (int d1 = 0; d1 < 3; ++d1)
#pragma unroll 1
        for (int d2 = 0; d2 < 3; ++d2) {
            const float* bp = base + d1 * GP3 + d2 * GP2;
#pragma unroll
            for (int d3 = 0; d3 < 3; ++d3)
#pragma unroll
                for (int d4 = 0; d4 < 3; ++d4) {
                    float v[4];
#pragma unroll
                    for (int m = 0; m < 4; ++m) v[m] = bp[m * 8 * GP + d3 * GP + d4];
                    int tap = ((d1 * 3 + d2) * 3 + d3) * 3 + d4;
#pragma unroll
                    for (int co = 0; co < 10; ++co) {
                        float w = W1[co * 81 + tap];
#pragma unroll
                        for (int m = 0; m < 4; ++m) acc[co][m] = fmaf(v[m], w, acc[co][m]);
                    }
                }
        }

    unsigned short* X2 = (unsigned short*)(ws + (size_t)z * SPASS + OFF_X2);
#pragma unroll
    for (int m = 0; m < 4; ++m) {
        int k = k0 + 8 * m;
        unsigned short* dst = X2 + ((size_t)(((i + 1) * 34 + (j + 1)) * 34 + (k + 1))) * 512
                              + l * 16;
        unsigned u[5];
#pragma unroll
        for (int c = 0; c < 5; ++c) {
            unsigned short lo = f2bf(fmaxf(acc[2 * c][m], 0.f));
            unsigned short hi = f2bf(fmaxf(acc[2 * c + 1][m], 0.f));
            u[c] = (unsigned)lo | ((unsigned)hi << 16);
        }
        ((uint4*)dst)[0] = make_uint4(u[0], u[1], u[2], u[3]);
        ((uint4*)dst)[1] = make_uint4(u[4], 0u, 0u, 0u);
    }
}

// ---------------------------------------------------------------
// conv2 via MFMA 32x32x16 bf16, N = (d4-shift,co) packing.
// block = 4 waves; wave wv handles 4 k-lines at k0=(w*4+wv)*4, w=blockIdx.z&1
// ---------------------------------------------------------------
__global__ __launch_bounds__(256) void k_conv2m(const unsigned* __restrict__ wsB,
                                                const float* __restrict__ B2,
                                                float* ws) {
    __shared__ unsigned Bl[27 * 64 * 4];
    __shared__ float epi[4][34 * 33];

    int t = threadIdx.x;
    int lane = t & 63, wv = t >> 6;
    int zslot = blockIdx.z >> 1, w = blockIdx.z & 1;
    int i = blockIdx.x, j = blockIdx.y;
    int k0 = (w * 4 + wv) * 4;

    for (int idx = t; idx < 27 * 64 * 4; idx += 256) Bl[idx] = wsB[idx];
    if (lane < 33) { epi[wv][lane] = 0.f; epi[wv][33 * 33 + lane] = 0.f; }
    __syncthreads();

    float* slot = ws + (size_t)zslot * SPASS;
    const unsigned short* X2 = (const unsigned short*)(slot + OFF_X2);
    // padded line index = (i+d1, j+d2, k0+kk); lane covers (l = lane&31, cin-half)
    const unsigned short* base0 = X2 + ((size_t)((i * 34 + j) * 34 + k0)) * 512
                                  + (lane & 31) * 16 + (lane >> 5) * 8;

    f32x16 D[4] = {};

#pragma unroll 1
    for (int d1 = 0; d1 < 3; ++d1)
#pragma unroll 1
        for (int d2 = 0; d2 < 3; ++d2) {
            int g = d1 * 3 + d2;
            const unsigned short* pg = base0 + (size_t)(d1 * 1156 + d2 * 34) * 512;
            bf16x8 A[6];
#pragma unroll
            for (int kk = 0; kk < 6; ++kk)
                A[kk] = *(const bf16x8*)(pg + kk * 512);
            bf16x8 Bf[3];
#pragma unroll
            for (int d3 = 0; d3 < 3; ++d3)
                Bf[d3] = *(const bf16x8*)&Bl[((g * 3 + d3) * 64 + lane) * 4];
#pragma unroll
            for (int kk = 0; kk < 6; ++kk)
#pragma unroll
                for (int m = 0; m < 4; ++m) {
                    int d3 = kk - m;
                    if (d3 >= 0 && d3 < 3)
                        D[m] = __builtin_amdgcn_mfma_f32_32x32x16_bf16(A[kk], Bf[d3], D[m], 0, 0, 0);
                }
        }

    // epilogue: shift-add along d4, bias, relu, store fp32 into padded bufB
    int q = lane & 31, half = lane >> 5;
    float* epw = epi[wv];
    float* bufB = slot + OFF_B;
#pragma unroll 1
    for (int m = 0; m < 4; ++m) {
#pragma unroll
        for (int r = 0; r < 16; ++r) {
            int row = (r & 3) + 8 * (r >> 2) + 4 * half;   // D row = l
            epw[(row + 1) * 33 + q] = D[m][r];             // col = n = lane&31
        }
#pragma unroll
        for (int c = 0; c < 5; ++c) {
            int co = half * 5 + c;
            float v = B2[co];
#pragma unroll
            for (int s = 0; s < 3; ++s)
                v += epw[(q + s) * 33 + s * 10 + co];
            bufB[(size_t)co * PX + POFF + (size_t)i * GP3 + j * GP2 + (k0 + m) * GP + q]
                = fmaxf(v, 0.f);
        }
    }
}

// ---------------------------------------------------------------
// conv3: 10 -> 1 channel, padded fp32 in (bufB), ReLU
// ---------------------------------------------------------------
__global__ __launch_bounds__(256) void k_conv3(const float* __restrict__ W3,
                                               const float* __restrict__ B3,
                                               float* ws, float* __restrict__ out,
                                               int p0) {
    int z = blockIdx.z;
    int p = p0 + z;
    int b = p >> 1, br = p & 1;
    int i = blockIdx.x, j = blockIdx.y;
    int t = threadIdx.x;
    int l = t & 31, k0 = t >> 5;
    const float* bufB = ws + (size_t)z * SPASS + OFF_B;

    float acc[4];
    float bb = B3[0];
#pragma unroll
    for (int m = 0; m < 4; ++m) acc[m] = bb;

#pragma unroll 1
    for (int cin = 0; cin < 10; ++cin) {
        const float* cbase = bufB + (size_t)cin * PX + POFF + (size_t)(i - 1) * GP3
                             + (j - 1) * GP2 + (k0 - 1) * GP + (l - 1);
#pragma unroll 1
        for (int d1 = 0; d1 < 3; ++d1)
#pragma unroll 1
            for (int d2 = 0; d2 < 3; ++d2) {
                const float* bp = cbase + d1 * GP3 + d2 * GP2;
#pragma unroll
                for (int d3 = 0; d3 < 3; ++d3)
#pragma unroll
                    for (int d4 = 0; d4 < 3; ++d4) {
                        int tap = ((d1 * 3 + d2) * 3 + d3) * 3 + d4;
                        float w = W3[cin * 81 + tap];
#pragma unroll
                        for (int m = 0; m < 4; ++m)
                            acc[m] = fmaf(bp[m * 8 * GP + d3 * GP + d4], w, acc[m]);
                    }
            }
    }

    float* dst = (br == 0) ? (out + (size_t)b * NPTS)
                           : (ws + (size_t)z * SPASS + OFF_OT);
#pragma unroll
    for (int m = 0; m < 4; ++m)
        dst[(size_t)i * 32768 + j * 1024 + (k0 + 8 * m) * 32 + l] = fmaxf(acc[m], 0.f);
}

// ---------------------------------------------------------------
// out[b] (as M[p][q], p=i*32+j, q=k*32+l) += out_t[q][p]
// ---------------------------------------------------------------
__global__ __launch_bounds__(256) void k_tadd(float* __restrict__ out,
                                              const float* __restrict__ ot) {
    __shared__ float tile[32][33];
    int tx = threadIdx.x, ty = threadIdx.y;   // (32,8)
    int P0 = blockIdx.x * 32, Q0 = blockIdx.y * 32;
#pragma unroll
    for (int r = 0; r < 4; ++r)
        tile[ty + 8 * r][tx] = ot[(size_t)(Q0 + ty + 8 * r) * 1024 + P0 + tx];
    __syncthreads();
#pragma unroll
    for (int r = 0; r < 4; ++r)
        out[(size_t)(P0 + ty + 8 * r) * 1024 + Q0 + tx] += tile[tx][ty + 8 * r];
}

// ---------------------------------------------------------------
extern "C" void kernel_launch(void* const* d_in, const int* in_sizes, int n_in,
                              void* d_out, int out_size, void* d_ws, size_t ws_size,
                              hipStream_t stream) {
    const float* x  = (const float*)d_in[0];
    const float* W1 = (const float*)d_in[1];
    const float* b1 = (const float*)d_in[2];
    const float* W2 = (const float*)d_in[3];
    const float* b2 = (const float*)d_in[4];
    const float* W3 = (const float*)d_in[5];
    const float* b3 = (const float*)d_in[6];
    float* out = (float*)d_out;
    float* ws  = (float*)d_ws;
    float* slots = ws + WSB_FLOATS;

    size_t slot_bytes = SPASS * sizeof(float);
    int Gn = (int)((ws_size - WSB_FLOATS * 4) / slot_bytes);
    if (Gn > 2) Gn = 2;
    if (Gn < 1) Gn = 1;

    size_t zb = WSB_FLOATS * 4 + (size_t)Gn * slot_bytes;
    if (zb > ws_size) zb = ws_size;
    hipMemsetAsync(d_ws, 0, zb, stream);   // zero halos + pack region once

    k_bpack<<<1, 256, 0, stream>>>(W2, (unsigned*)ws);

    for (int p0 = 0; p0 < 8; p0 += Gn) {
        int g = 8 - p0 < Gn ? 8 - p0 : Gn;
        k_copy_in<<<dim3(4096, 1, g), 256, 0, stream>>>(x, slots, p0);
        k_conv1<<<dim3(32, 32, g), 256, 0, stream>>>(W1, b1, slots, p0);
        k_conv2m<<<dim3(32, 32, 2 * g), 256, 0, stream>>>((unsigned*)ws, b2, slots);
        k_conv3<<<dim3(32, 32, g), 256, 0, stream>>>(W3, b3, slots, out, p0);
        for (int p = p0; p < p0 + g; ++p)
            if (p & 1)
                k_tadd<<<dim3(32, 32), dim3(32, 8), 0, stream>>>(
                    out + (size_t)(p >> 1) * NPTS,
                    slots + (size_t)(p - p0) * SPASS + OFF_OT);
    }
}

// Round 3
// 1208.050 us; speedup vs baseline: 2.1507x; 1.7462x over previous
//
#include <hip/hip_runtime.h>

// ---- geometry ----
#define GSZ 32
#define GP 34                    // padded (+1 halo each side)
#define GP2 (GP*GP)              // 1156
#define GP3 (GP*GP2)             // 39304
#define PX  (GP*GP3)             // 1336336 floats per padded fp32 channel
#define POFF (GP3+GP2+GP+1)      // offset of (0,0,0,0) inside padded channel
#define NPTS (1<<20)             // 32^4

// X-layout: bf16 [34][34][34][32][16]  (i,j,k padded; l=32; c padded to 16)
#define XT_FLOATS ((size_t)34*34*34*32*8)   // 10,061,824 float-equivalents

// per-pass slot layout (float units)
#define OFF_XIN ((size_t)0)
#define OFF_X2  ((size_t)PX)
#define OFF_X3  (OFF_X2 + XT_FLOATS)
#define OFF_OT  (OFF_X3 + XT_FLOATS)
#define SPASS   (OFF_OT + (size_t)NPTS)     // 22,508,560 floats = 90.0 MB

#define WSB_FLOATS 16384   // packed-B region: wsB2 27648B @0, wsB3 9216B @27648

typedef __attribute__((ext_vector_type(8)))  short bf16x8;
typedef __attribute__((ext_vector_type(16))) float f32x16;

__device__ __forceinline__ unsigned short f2bf(float f) {
    union { float f; unsigned u; } v; v.f = f;
    unsigned r = v.u + 0x7FFFu + ((v.u >> 16) & 1u);   // RNE
    return (unsigned short)(r >> 16);
}

// ---------------------------------------------------------------
// pack W2: wsB2[g3][lane][4] u32, g3=(d1*3+d2)*3+d3; B[k=cin][n=d4*10+co]
// ---------------------------------------------------------------
__global__ void k_bpack2(const float* __restrict__ W2, unsigned* __restrict__ wsB) {
    int t = threadIdx.x;
    int lane = t & 63, j = t >> 6;
    int n = lane & 31, kh = lane >> 5;
    for (int g = 0; g < 27; ++g) {
        unsigned v = 0;
        for (int e = 0; e < 2; ++e) {
            int k = kh * 8 + 2 * j + e;
            unsigned short h = 0;
            if (k < 10 && n < 30) {
                int co = n % 10, d4 = n / 10;
                h = f2bf(W2[(co * 10 + k) * 81 + g * 3 + d4]);
            }
            v |= (unsigned)h << (16 * e);
        }
        wsB[(g * 64 + lane) * 4 + j] = v;
    }
}

// ---------------------------------------------------------------
// pack W3: wsB3[g9][lane][4] u32, g9=d1*3+d2; B[k=cin][n=d3*3+d4]
// ---------------------------------------------------------------
__global__ void k_bpack3(const float* __restrict__ W3, unsigned* __restrict__ wsB3) {
    int t = threadIdx.x;
    int lane = t & 63, j = t >> 6;
    int n = lane & 31, kh = lane >> 5;
    for (int g = 0; g < 9; ++g) {
        unsigned v = 0;
        for (int e = 0; e < 2; ++e) {
            int k = kh * 8 + 2 * j + e;
            unsigned short h = 0;
            if (k < 10 && n < 9) {
                int d3 = n / 3, d4 = n % 3;
                h = f2bf(W3[k * 81 + (g * 3 + d3) * 3 + d4]);
            }
            v |= (unsigned)h << (16 * e);
        }
        wsB3[(g * 64 + lane) * 4 + j] = v;
    }
}

// ---------------------------------------------------------------
// copy input (branch 0: identity, branch 1: (i,j,k,l)<-(k,l,i,j))
// ---------------------------------------------------------------
__global__ __launch_bounds__(256) void k_copy_in(const float* __restrict__ x,
                                                 float* __restrict__ ws, int p0) {
    int p = p0 + blockIdx.z;
    int b = p >> 1, br = p & 1;
    int gid = blockIdx.x * 256 + threadIdx.x;
    int l = gid & 31, k = (gid >> 5) & 31, j = (gid >> 10) & 31, i = gid >> 15;
    const float* xb = x + (size_t)b * NPTS;
    float v;
    if (br == 0) v = xb[gid];
    else         v = xb[(((k * 32 + l) * 32 + i) * 32) + j];
    float* xin = ws + (size_t)blockIdx.z * SPASS + OFF_XIN;
    xin[POFF + i * GP3 + j * GP2 + k * GP + l] = v;
}

// ---------------------------------------------------------------
// conv1: 1 -> 10, fp32 padded in, bf16 X2 out, ReLU
// ---------------------------------------------------------------
__global__ __launch_bounds__(256) void k_conv1(const float* __restrict__ W1,
                                               const float* __restrict__ B1,
                                               float* ws, int p0) {
    int z = blockIdx.z;
    int i = blockIdx.x, j = blockIdx.y;
    int t = threadIdx.x;
    int l = t & 31, k0 = t >> 5;
    const float* xin = ws + (size_t)z * SPASS + OFF_XIN;

    float acc[10][4];
#pragma unroll
    for (int co = 0; co < 10; ++co) {
        float bb = B1[co];
#pragma unroll
        for (int m = 0; m < 4; ++m) acc[co][m] = bb;
    }

    const float* base = xin + POFF + (size_t)(i - 1) * GP3 + (j - 1) * GP2
                        + (k0 - 1) * GP + (l - 1);
#pragma unroll 1
    for (int d1 = 0; d1 < 3; ++d1)
#pragma unroll 1
        for (int d2 = 0; d2 < 3; ++d2) {
            const float* bp = base + d1 * GP3 + d2 * GP2;
#pragma unroll
            for (int d3 = 0; d3 < 3; ++d3)
#pragma unroll
                for (int d4 = 0; d4 < 3; ++d4) {
                    float v[4];
#pragma unroll
                    for (int m = 0; m < 4; ++m) v[m] = bp[m * 8 * GP + d3 * GP + d4];
                    int tap = ((d1 * 3 + d2) * 3 + d3) * 3 + d4;
#pragma unroll
                    for (int co = 0; co < 10; ++co) {
                        float w = W1[co * 81 + tap];
#pragma unroll
                        for (int m = 0; m < 4; ++m) acc[co][m] = fmaf(v[m], w, acc[co][m]);
                    }
                }
        }

    unsigned short* X2 = (unsigned short*)(ws + (size_t)z * SPASS + OFF_X2);
#pragma unroll
    for (int m = 0; m < 4; ++m) {
        int k = k0 + 8 * m;
        unsigned short* dst = X2 + ((size_t)(((i + 1) * 34 + (j + 1)) * 34 + (k + 1))) * 512
                              + l * 16;
        unsigned u[5];
#pragma unroll
        for (int c = 0; c < 5; ++c) {
            unsigned short lo = f2bf(fmaxf(acc[2 * c][m], 0.f));
            unsigned short hi = f2bf(fmaxf(acc[2 * c + 1][m], 0.f));
            u[c] = (unsigned)lo | ((unsigned)hi << 16);
        }
        ((uint4*)dst)[0] = make_uint4(u[0], u[1], u[2], u[3]);
        ((uint4*)dst)[1] = make_uint4(u[4], 0u, 0u, 0u);
    }
}

// ---------------------------------------------------------------
// conv2 via MFMA 32x32x16 bf16, N=(d4,co). bf16 X3 output lines.
// grid (1024,1,2g); XCD-chunked swizzle on (i,j)
// ---------------------------------------------------------------
__global__ __launch_bounds__(256) void k_conv2m(const unsigned* __restrict__ wsB,
                                                const float* __restrict__ B2,
                                                float* ws) {
    __shared__ unsigned Bl[27 * 64 * 4];
    __shared__ float epi[4][34 * 33];

    int t = threadIdx.x;
    int lane = t & 63, wv = t >> 6;
    int zslot = blockIdx.z >> 1, w = blockIdx.z & 1;
    int bid = blockIdx.x;
    int s = ((bid & 7) << 7) | (bid >> 3);
    int i = s >> 5, j = s & 31;
    int k0 = (w * 4 + wv) * 4;

    for (int idx = t; idx < 27 * 64 * 4; idx += 256) Bl[idx] = wsB[idx];
    if (lane < 33) { epi[wv][lane] = 0.f; epi[wv][33 * 33 + lane] = 0.f; }
    __syncthreads();

    float* slot = ws + (size_t)zslot * SPASS;
    const unsigned short* X2 = (const unsigned short*)(slot + OFF_X2);
    const unsigned short* base0 = X2 + ((size_t)((i * 34 + j) * 34 + k0)) * 512
                                  + (lane & 31) * 16 + (lane >> 5) * 8;

    f32x16 D[4] = {};

#pragma unroll 1
    for (int d1 = 0; d1 < 3; ++d1)
#pragma unroll 1
        for (int d2 = 0; d2 < 3; ++d2) {
            int g = d1 * 3 + d2;
            const unsigned short* pg = base0 + (size_t)(d1 * 1156 + d2 * 34) * 512;
            bf16x8 A[6];
#pragma unroll
            for (int kk = 0; kk < 6; ++kk)
                A[kk] = *(const bf16x8*)(pg + kk * 512);
            bf16x8 Bf[3];
#pragma unroll
            for (int d3 = 0; d3 < 3; ++d3)
                Bf[d3] = *(const bf16x8*)&Bl[((g * 3 + d3) * 64 + lane) * 4];
#pragma unroll
            for (int kk = 0; kk < 6; ++kk)
#pragma unroll
                for (int m = 0; m < 4; ++m) {
                    int d3 = kk - m;
                    if (d3 >= 0 && d3 < 3)
                        D[m] = __builtin_amdgcn_mfma_f32_32x32x16_bf16(A[kk], Bf[d3], D[m], 0, 0, 0);
                }
        }

    // epilogue: shift-add along d4, bias, relu, pack bf16 X3 line, coalesced store
    int q = lane & 31, half = lane >> 5;
    float* epw = epi[wv];
    unsigned short* X3 = (unsigned short*)(slot + OFF_X3);
#pragma unroll 1
    for (int m = 0; m < 4; ++m) {
#pragma unroll
        for (int r = 0; r < 16; ++r) {
            int row = (r & 3) + 8 * (r >> 2) + 4 * half;   // D row = l
            epw[(row + 1) * 33 + q] = D[m][r];             // col = n
        }
        unsigned u[4];
#pragma unroll
        for (int e = 0; e < 4; ++e) {
            unsigned short h2[2];
#pragma unroll
            for (int x = 0; x < 2; ++x) {
                int co = half * 8 + 2 * e + x;
                float v = 0.f;
                if (co < 10) {
                    v = B2[co];
#pragma unroll
                    for (int ss = 0; ss < 3; ++ss)
                        v += epw[(q + ss) * 33 + ss * 10 + co];
                    v = fmaxf(v, 0.f);
                }
                h2[x] = f2bf(v);
            }
            u[e] = (unsigned)h2[0] | ((unsigned)h2[1] << 16);
        }
        unsigned short* dst = X3 + ((size_t)(((i + 1) * 34 + (j + 1)) * 34 + (k0 + m + 1))) * 512
                              + q * 16 + half * 8;
        *(uint4*)dst = make_uint4(u[0], u[1], u[2], u[3]);
    }
}

// ---------------------------------------------------------------
// conv3 via MFMA 32x32x16 bf16, N=(d3,d4) 2D-shift packing, 10->1
// D[rel][l][(d3,d4)] accumulated over (d1,d2,cin); epilogue combines
// line-shifts (regs) and l-shifts (LDS).
// ---------------------------------------------------------------
__global__ __launch_bounds__(256) void k_conv3m(const unsigned* __restrict__ wsB3,
                                                const float* __restrict__ B3,
                                                float* ws, float* __restrict__ out,
                                                int p0) {
    __shared__ unsigned Bl[9 * 64 * 4];
    __shared__ float epi[4][6 * 34 * 9];

    int t = threadIdx.x;
    int lane = t & 63, wv = t >> 6;
    int zslot = blockIdx.z >> 1, w = blockIdx.z & 1;
    int p = p0 + zslot;
    int b = p >> 1, br = p & 1;
    int bid = blockIdx.x;
    int s = ((bid & 7) << 7) | (bid >> 3);
    int i = s >> 5, j = s & 31;
    int k0 = (w * 4 + wv) * 4;

    for (int idx = t; idx < 9 * 64 * 4; idx += 256) Bl[idx] = wsB3[idx];
    for (int idx = lane; idx < 6 * 9; idx += 64) {
        int rel = idx / 9, c = idx % 9;
        epi[wv][(rel * 34 + 0) * 9 + c] = 0.f;
        epi[wv][(rel * 34 + 33) * 9 + c] = 0.f;
    }
    __syncthreads();

    float* slot = ws + (size_t)zslot * SPASS;
    const unsigned short* X3 = (const unsigned short*)(slot + OFF_X3);
    const unsigned short* base0 = X3 + ((size_t)((i * 34 + j) * 34 + k0)) * 512
                                  + (lane & 31) * 16 + (lane >> 5) * 8;

    f32x16 D[6] = {};

#pragma unroll 1
    for (int g = 0; g < 9; ++g) {
        const unsigned short* pg = base0 + (size_t)((g / 3) * 1156 + (g % 3) * 34) * 512;
        bf16x8 Bf = *(const bf16x8*)&Bl[(g * 64 + lane) * 4];
#pragma unroll
        for (int rel = 0; rel < 6; ++rel) {
            bf16x8 A = *(const bf16x8*)(pg + rel * 512);
            D[rel] = __builtin_amdgcn_mfma_f32_32x32x16_bf16(A, Bf, D[rel], 0, 0, 0);
        }
    }

    int q = lane & 31, half = lane >> 5;
    float* epw = epi[wv];
    if (q < 9) {
#pragma unroll
        for (int rel = 0; rel < 6; ++rel)
#pragma unroll
            for (int r = 0; r < 16; ++r) {
                int row = (r & 3) + 8 * (r >> 2) + 4 * half;
                epw[(rel * 34 + row + 1) * 9 + q] = D[rel][r];
            }
    }
    // per-wave LDS: within-wave waitcnt ordering suffices (no barrier)
    float bb = B3[0];
    float vout[4];
#pragma unroll
    for (int m = 0; m < 4; ++m) {
        float v = bb;
#pragma unroll
        for (int d3 = 0; d3 < 3; ++d3)
#pragma unroll
            for (int d4 = 0; d4 < 3; ++d4)
                v += epw[((m + d3) * 34 + (q + d4)) * 9 + d3 * 3 + d4];
        vout[m] = fmaxf(v, 0.f);
    }

    float* dst = (br == 0) ? (out + (size_t)b * NPTS) : (slot + OFF_OT);
    if (half == 0)
#pragma unroll
        for (int m = 0; m < 4; ++m)
            dst[(size_t)i * 32768 + j * 1024 + (k0 + m) * 32 + q] = vout[m];
}

// ---------------------------------------------------------------
// out[b] (as M[p][q]) += ot[q][p]
// ---------------------------------------------------------------
__global__ __launch_bounds__(256) void k_tadd(float* __restrict__ out,
                                              const float* __restrict__ ot) {
    __shared__ float tile[32][33];
    int tx = threadIdx.x, ty = threadIdx.y;   // (32,8)
    int P0 = blockIdx.x * 32, Q0 = blockIdx.y * 32;
#pragma unroll
    for (int r = 0; r < 4; ++r)
        tile[ty + 8 * r][tx] = ot[(size_t)(Q0 + ty + 8 * r) * 1024 + P0 + tx];
    __syncthreads();
#pragma unroll
    for (int r = 0; r < 4; ++r)
        out[(size_t)(P0 + ty + 8 * r) * 1024 + Q0 + tx] += tile[tx][ty + 8 * r];
}

// ---------------------------------------------------------------
extern "C" void kernel_launch(void* const* d_in, const int* in_sizes, int n_in,
                              void* d_out, int out_size, void* d_ws, size_t ws_size,
                              hipStream_t stream) {
    const float* x  = (const float*)d_in[0];
    const float* W1 = (const float*)d_in[1];
    const float* b1 = (const float*)d_in[2];
    const float* W2 = (const float*)d_in[3];
    const float* b2 = (const float*)d_in[4];
    const float* W3 = (const float*)d_in[5];
    const float* b3 = (const float*)d_in[6];
    float* out = (float*)d_out;
    float* ws  = (float*)d_ws;
    float* slots = ws + WSB_FLOATS;
    unsigned* wsB2 = (unsigned*)ws;
    unsigned* wsB3 = (unsigned*)ws + 6912;

    size_t slot_bytes = SPASS * sizeof(float);
    int Gn = (int)((ws_size - WSB_FLOATS * 4) / slot_bytes);
    if (Gn > 2) Gn = 2;
    if (Gn < 1) Gn = 1;

    size_t zb = WSB_FLOATS * 4 + (size_t)Gn * slot_bytes;
    if (zb > ws_size) zb = ws_size;
    hipMemsetAsync(d_ws, 0, zb, stream);   // zero halos + pack region once

    k_bpack2<<<1, 256, 0, stream>>>(W2, wsB2);
    k_bpack3<<<1, 256, 0, stream>>>(W3, wsB3);

    for (int p0 = 0; p0 < 8; p0 += Gn) {
        int g = 8 - p0 < Gn ? 8 - p0 : Gn;
        k_copy_in<<<dim3(4096, 1, g), 256, 0, stream>>>(x, slots, p0);
        k_conv1<<<dim3(32, 32, g), 256, 0, stream>>>(W1, b1, slots, p0);
        k_conv2m<<<dim3(1024, 1, 2 * g), 256, 0, stream>>>(wsB2, b2, slots);
        k_conv3m<<<dim3(1024, 1, 2 * g), 256, 0, stream>>>(wsB3, b3, slots, out, p0);
        for (int p = p0; p < p0 + g; ++p)
            if (p & 1)
                k_tadd<<<dim3(32, 32), dim3(32, 8), 0, stream>>>(
                    out + (size_t)(p >> 1) * NPTS,
                    slots + (size_t)(p - p0) * SPASS + OFF_OT);
    }
}

// Round 4
// 763.859 us; speedup vs baseline: 3.4013x; 1.5815x over previous
//
#include <hip/hip_runtime.h>

// ---- geometry ----
#define GSZ 32
#define GP 34                    // padded (+1 halo each side)
#define GP2 (GP*GP)              // 1156
#define GP3 (GP*GP2)             // 39304
#define PX  (GP*GP3)             // 1336336 floats per padded fp32 channel
#define POFF (GP3+GP2+GP+1)      // offset of (0,0,0,0) inside padded channel
#define NPTS (1<<20)             // 32^4

// X-layout: bf16 [34][34][34][32][16]  (i,j,k padded; l=32; c padded to 16)
#define XT_FLOATS ((size_t)34*34*34*32*8)   // 10,061,824 float-equivalents

// per-pass slot layout (float units)
#define OFF_XIN ((size_t)0)
#define OFF_X2  ((size_t)PX)
#define OFF_X3  (OFF_X2 + XT_FLOATS)
#define OFF_OT  (OFF_X3 + XT_FLOATS)
#define SPASS   (OFF_OT + (size_t)NPTS)     // 22,508,560 floats = 90.0 MB

#define WSB_FLOATS 16384   // packed-B region: wsB2 27648B @0, wsB3 9216B @27648

typedef __attribute__((ext_vector_type(8)))  short bf16x8;
typedef __attribute__((ext_vector_type(16))) float f32x16;

__device__ __forceinline__ unsigned short f2bf(float f) {
    union { float f; unsigned u; } v; v.f = f;
    unsigned r = v.u + 0x7FFFu + ((v.u >> 16) & 1u);   // RNE
    return (unsigned short)(r >> 16);
}

// ---------------------------------------------------------------
// pack W2: wsB2[g3][lane][4] u32, g3=(d1*3+d2)*3+d3; B[k=cin][n=d4*10+co]
// ---------------------------------------------------------------
__global__ void k_bpack2(const float* __restrict__ W2, unsigned* __restrict__ wsB) {
    int t = threadIdx.x;
    int lane = t & 63, j = t >> 6;
    int n = lane & 31, kh = lane >> 5;
    for (int g = 0; g < 27; ++g) {
        unsigned v = 0;
        for (int e = 0; e < 2; ++e) {
            int k = kh * 8 + 2 * j + e;
            unsigned short h = 0;
            if (k < 10 && n < 30) {
                int co = n % 10, d4 = n / 10;
                h = f2bf(W2[(co * 10 + k) * 81 + g * 3 + d4]);
            }
            v |= (unsigned)h << (16 * e);
        }
        wsB[(g * 64 + lane) * 4 + j] = v;
    }
}

// ---------------------------------------------------------------
// pack W3: wsB3[g9][lane][4] u32, g9=d1*3+d2; B[k=cin][n=d3*3+d4]
// ---------------------------------------------------------------
__global__ void k_bpack3(const float* __restrict__ W3, unsigned* __restrict__ wsB3) {
    int t = threadIdx.x;
    int lane = t & 63, j = t >> 6;
    int n = lane & 31, kh = lane >> 5;
    for (int g = 0; g < 9; ++g) {
        unsigned v = 0;
        for (int e = 0; e < 2; ++e) {
            int k = kh * 8 + 2 * j + e;
            unsigned short h = 0;
            if (k < 10 && n < 9) {
                int d3 = n / 3, d4 = n % 3;
                h = f2bf(W3[k * 81 + (g * 3 + d3) * 3 + d4]);
            }
            v |= (unsigned)h << (16 * e);
        }
        wsB3[(g * 64 + lane) * 4 + j] = v;
    }
}

// ---------------------------------------------------------------
// copy input (branch 0: identity, branch 1: (i,j,k,l)<-(k,l,i,j))
// ---------------------------------------------------------------
__global__ __launch_bounds__(256) void k_copy_in(const float* __restrict__ x,
                                                 float* __restrict__ ws, int p0) {
    int p = p0 + blockIdx.z;
    int b = p >> 1, br = p & 1;
    int gid = blockIdx.x * 256 + threadIdx.x;
    int l = gid & 31, k = (gid >> 5) & 31, j = (gid >> 10) & 31, i = gid >> 15;
    const float* xb = x + (size_t)b * NPTS;
    float v;
    if (br == 0) v = xb[gid];
    else         v = xb[(((k * 32 + l) * 32 + i) * 32) + j];
    float* xin = ws + (size_t)blockIdx.z * SPASS + OFF_XIN;
    xin[POFF + i * GP3 + j * GP2 + k * GP + l] = v;
}

// ---------------------------------------------------------------
// conv1: 1 -> 10, fp32 padded in, bf16 X2 out, ReLU
// ---------------------------------------------------------------
__global__ __launch_bounds__(256) void k_conv1(const float* __restrict__ W1,
                                               const float* __restrict__ B1,
                                               float* ws, int p0) {
    int z = blockIdx.z;
    int i = blockIdx.x, j = blockIdx.y;
    int t = threadIdx.x;
    int l = t & 31, k0 = t >> 5;
    const float* xin = ws + (size_t)z * SPASS + OFF_XIN;

    float acc[10][4];
#pragma unroll
    for (int co = 0; co < 10; ++co) {
        float bb = B1[co];
#pragma unroll
        for (int m = 0; m < 4; ++m) acc[co][m] = bb;
    }

    const float* base = xin + POFF + (size_t)(i - 1) * GP3 + (j - 1) * GP2
                        + (k0 - 1) * GP + (l - 1);
#pragma unroll 1
    for (int d1 = 0; d1 < 3; ++d1)
#pragma unroll 1
        for (int d2 = 0; d2 < 3; ++d2) {
            const float* bp = base + d1 * GP3 + d2 * GP2;
#pragma unroll
            for (int d3 = 0; d3 < 3; ++d3)
#pragma unroll
                for (int d4 = 0; d4 < 3; ++d4) {
                    float v[4];
#pragma unroll
                    for (int m = 0; m < 4; ++m) v[m] = bp[m * 8 * GP + d3 * GP + d4];
                    int tap = ((d1 * 3 + d2) * 3 + d3) * 3 + d4;
#pragma unroll
                    for (int co = 0; co < 10; ++co) {
                        float w = W1[co * 81 + tap];
#pragma unroll
                        for (int m = 0; m < 4; ++m) acc[co][m] = fmaf(v[m], w, acc[co][m]);
                    }
                }
        }

    unsigned short* X2 = (unsigned short*)(ws + (size_t)z * SPASS + OFF_X2);
#pragma unroll
    for (int m = 0; m < 4; ++m) {
        int k = k0 + 8 * m;
        unsigned short* dst = X2 + ((size_t)(((i + 1) * 34 + (j + 1)) * 34 + (k + 1))) * 512
                              + l * 16;
        unsigned u[5];
#pragma unroll
        for (int c = 0; c < 5; ++c) {
            unsigned short lo = f2bf(fmaxf(acc[2 * c][m], 0.f));
            unsigned short hi = f2bf(fmaxf(acc[2 * c + 1][m], 0.f));
            u[c] = (unsigned)lo | ((unsigned)hi << 16);
        }
        ((uint4*)dst)[0] = make_uint4(u[0], u[1], u[2], u[3]);
        ((uint4*)dst)[1] = make_uint4(u[4], 0u, 0u, 0u);
    }
}

// ---------------------------------------------------------------
// conv2 via MFMA 32x32x16 bf16, N=(d4,co). bf16 X3 output lines.
// grid (1024,1,2g); XCD-chunked swizzle on (i,j).
// NOTE: epilogue m-loop is FULLY unrolled — any runtime index into D[]
// demotes the accumulators to scratch (rule #20; R3's 590MB write bug).
// ---------------------------------------------------------------
__global__ __launch_bounds__(256) void k_conv2m(const unsigned* __restrict__ wsB,
                                                const float* __restrict__ B2,
                                                float* ws) {
    __shared__ unsigned Bl[27 * 64 * 4];
    __shared__ float epi[4][34 * 33];

    int t = threadIdx.x;
    int lane = t & 63, wv = t >> 6;
    int zslot = blockIdx.z >> 1, w = blockIdx.z & 1;
    int bid = blockIdx.x;
    int s = ((bid & 7) << 7) | (bid >> 3);
    int i = s >> 5, j = s & 31;
    int k0 = (w * 4 + wv) * 4;

    for (int idx = t; idx < 27 * 64 * 4; idx += 256) Bl[idx] = wsB[idx];
    if (lane < 33) { epi[wv][lane] = 0.f; epi[wv][33 * 33 + lane] = 0.f; }

    int q = lane & 31, half = lane >> 5;
    // hoist bias: thread handles co = half*8 + 2e + x
    float bias[8];
#pragma unroll
    for (int e = 0; e < 8; ++e) {
        int co = half * 8 + e;
        bias[e] = (co < 10) ? B2[co] : 0.f;
    }
    __syncthreads();

    float* slot = ws + (size_t)zslot * SPASS;
    const unsigned short* X2 = (const unsigned short*)(slot + OFF_X2);
    const unsigned short* base0 = X2 + ((size_t)((i * 34 + j) * 34 + k0)) * 512
                                  + q * 16 + half * 8;

    f32x16 D[4] = {};

#pragma unroll 1
    for (int d1 = 0; d1 < 3; ++d1)
#pragma unroll 1
        for (int d2 = 0; d2 < 3; ++d2) {
            int g = d1 * 3 + d2;
            const unsigned short* pg = base0 + (size_t)(d1 * 1156 + d2 * 34) * 512;
            bf16x8 A[6];
#pragma unroll
            for (int kk = 0; kk < 6; ++kk)
                A[kk] = *(const bf16x8*)(pg + kk * 512);
            bf16x8 Bf[3];
#pragma unroll
            for (int d3 = 0; d3 < 3; ++d3)
                Bf[d3] = *(const bf16x8*)&Bl[((g * 3 + d3) * 64 + lane) * 4];
#pragma unroll
            for (int kk = 0; kk < 6; ++kk)
#pragma unroll
                for (int m = 0; m < 4; ++m) {
                    int d3 = kk - m;
                    if (d3 >= 0 && d3 < 3)
                        D[m] = __builtin_amdgcn_mfma_f32_32x32x16_bf16(A[kk], Bf[d3], D[m], 0, 0, 0);
                }
        }

    // epilogue: shift-add along d4, bias, relu, pack bf16 X3 line, coalesced store
    float* epw = epi[wv];
    unsigned short* X3 = (unsigned short*)(slot + OFF_X3);
#pragma unroll
    for (int m = 0; m < 4; ++m) {
#pragma unroll
        for (int r = 0; r < 16; ++r) {
            int row = (r & 3) + 8 * (r >> 2) + 4 * half;   // D row = l
            epw[(row + 1) * 33 + q] = D[m][r];             // col = n
        }
        unsigned u[4];
#pragma unroll
        for (int e = 0; e < 4; ++e) {
            unsigned short h2[2];
#pragma unroll
            for (int x = 0; x < 2; ++x) {
                int co = half * 8 + 2 * e + x;
                float v = 0.f;
                if (co < 10) {
                    v = bias[2 * e + x];
#pragma unroll
                    for (int ss = 0; ss < 3; ++ss)
                        v += epw[(q + ss) * 33 + ss * 10 + co];
                    v = fmaxf(v, 0.f);
                }
                h2[x] = f2bf(v);
            }
            u[e] = (unsigned)h2[0] | ((unsigned)h2[1] << 16);
        }
        unsigned short* dst = X3 + ((size_t)(((i + 1) * 34 + (j + 1)) * 34 + (k0 + m + 1))) * 512
                              + q * 16 + half * 8;
        *(uint4*)dst = make_uint4(u[0], u[1], u[2], u[3]);
    }
}

// ---------------------------------------------------------------
// conv3 via MFMA 32x32x16 bf16, N=(d3,d4) 2D-shift packing, 10->1
// ---------------------------------------------------------------
__global__ __launch_bounds__(256) void k_conv3m(const unsigned* __restrict__ wsB3,
                                                const float* __restrict__ B3,
                                                float* ws, float* __restrict__ out,
                                                int p0) {
    __shared__ unsigned Bl[9 * 64 * 4];
    __shared__ float epi[4][6 * 34 * 9];

    int t = threadIdx.x;
    int lane = t & 63, wv = t >> 6;
    int zslot = blockIdx.z >> 1, w = blockIdx.z & 1;
    int p = p0 + zslot;
    int b = p >> 1, br = p & 1;
    int bid = blockIdx.x;
    int s = ((bid & 7) << 7) | (bid >> 3);
    int i = s >> 5, j = s & 31;
    int k0 = (w * 4 + wv) * 4;

    for (int idx = t; idx < 9 * 64 * 4; idx += 256) Bl[idx] = wsB3[idx];
    for (int idx = lane; idx < 6 * 9; idx += 64) {
        int rel = idx / 9, c = idx % 9;
        epi[wv][(rel * 34 + 0) * 9 + c] = 0.f;
        epi[wv][(rel * 34 + 33) * 9 + c] = 0.f;
    }
    __syncthreads();

    float* slot = ws + (size_t)zslot * SPASS;
    const unsigned short* X3 = (const unsigned short*)(slot + OFF_X3);
    const unsigned short* base0 = X3 + ((size_t)((i * 34 + j) * 34 + k0)) * 512
                                  + (lane & 31) * 16 + (lane >> 5) * 8;

    f32x16 D[6] = {};

#pragma unroll 1
    for (int g = 0; g < 9; ++g) {
        const unsigned short* pg = base0 + (size_t)((g / 3) * 1156 + (g % 3) * 34) * 512;
        bf16x8 Bf = *(const bf16x8*)&Bl[(g * 64 + lane) * 4];
#pragma unroll
        for (int rel = 0; rel < 6; ++rel) {
            bf16x8 A = *(const bf16x8*)(pg + rel * 512);
            D[rel] = __builtin_amdgcn_mfma_f32_32x32x16_bf16(A, Bf, D[rel], 0, 0, 0);
        }
    }

    int q = lane & 31, half = lane >> 5;
    float* epw = epi[wv];
    if (q < 9) {
#pragma unroll
        for (int rel = 0; rel < 6; ++rel)
#pragma unroll
            for (int r = 0; r < 16; ++r) {
                int row = (r & 3) + 8 * (r >> 2) + 4 * half;
                epw[(rel * 34 + row + 1) * 9 + q] = D[rel][r];
            }
    }
    // per-wave LDS: within-wave in-order LDS suffices (no barrier)
    float bb = B3[0];
    float vout[4];
#pragma unroll
    for (int m = 0; m < 4; ++m) {
        float v = bb;
#pragma unroll
        for (int d3 = 0; d3 < 3; ++d3)
#pragma unroll
            for (int d4 = 0; d4 < 3; ++d4)
                v += epw[((m + d3) * 34 + (q + d4)) * 9 + d3 * 3 + d4];
        vout[m] = fmaxf(v, 0.f);
    }

    float* dst = (br == 0) ? (out + (size_t)b * NPTS) : (slot + OFF_OT);
    if (half == 0)
#pragma unroll
        for (int m = 0; m < 4; ++m)
            dst[(size_t)i * 32768 + j * 1024 + (k0 + m) * 32 + q] = vout[m];
}

// ---------------------------------------------------------------
// out[b] (as M[p][q]) += ot[q][p]
// ---------------------------------------------------------------
__global__ __launch_bounds__(256) void k_tadd(float* __restrict__ out,
                                              const float* __restrict__ ot) {
    __shared__ float tile[32][33];
    int tx = threadIdx.x, ty = threadIdx.y;   // (32,8)
    int P0 = blockIdx.x * 32, Q0 = blockIdx.y * 32;
#pragma unroll
    for (int r = 0; r < 4; ++r)
        tile[ty + 8 * r][tx] = ot[(size_t)(Q0 + ty + 8 * r) * 1024 + P0 + tx];
    __syncthreads();
#pragma unroll
    for (int r = 0; r < 4; ++r)
        out[(size_t)(P0 + ty + 8 * r) * 1024 + Q0 + tx] += tile[tx][ty + 8 * r];
}

// ---------------------------------------------------------------
extern "C" void kernel_launch(void* const* d_in, const int* in_sizes, int n_in,
                              void* d_out, int out_size, void* d_ws, size_t ws_size,
                              hipStream_t stream) {
    const float* x  = (const float*)d_in[0];
    const float* W1 = (const float*)d_in[1];
    const float* b1 = (const float*)d_in[2];
    const float* W2 = (const float*)d_in[3];
    const float* b2 = (const float*)d_in[4];
    const float* W3 = (const float*)d_in[5];
    const float* b3 = (const float*)d_in[6];
    float* out = (float*)d_out;
    float* ws  = (float*)d_ws;
    float* slots = ws + WSB_FLOATS;
    unsigned* wsB2 = (unsigned*)ws;
    unsigned* wsB3 = (unsigned*)ws + 6912;

    size_t slot_bytes = SPASS * sizeof(float);
    int Gn = (int)((ws_size - WSB_FLOATS * 4) / slot_bytes);
    if (Gn > 2) Gn = 2;
    if (Gn < 1) Gn = 1;

    size_t zb = WSB_FLOATS * 4 + (size_t)Gn * slot_bytes;
    if (zb > ws_size) zb = ws_size;
    hipMemsetAsync(d_ws, 0, zb, stream);   // zero halos + pack region once

    k_bpack2<<<1, 256, 0, stream>>>(W2, wsB2);
    k_bpack3<<<1, 256, 0, stream>>>(W3, wsB3);

    for (int p0 = 0; p0 < 8; p0 += Gn) {
        int g = 8 - p0 < Gn ? 8 - p0 : Gn;
        k_copy_in<<<dim3(4096, 1, g), 256, 0, stream>>>(x, slots, p0);
        k_conv1<<<dim3(32, 32, g), 256, 0, stream>>>(W1, b1, slots, p0);
        k_conv2m<<<dim3(1024, 1, 2 * g), 256, 0, stream>>>(wsB2, b2, slots);
        k_conv3m<<<dim3(1024, 1, 2 * g), 256, 0, stream>>>(wsB3, b3, slots, out, p0);
        for (int p = p0; p < p0 + g; ++p)
            if (p & 1)
                k_tadd<<<dim3(32, 32), dim3(32, 8), 0, stream>>>(
                    out + (size_t)(p >> 1) * NPTS,
                    slots + (size_t)(p - p0) * SPASS + OFF_OT);
    }
}

// Round 5
// 712.963 us; speedup vs baseline: 3.6441x; 1.0714x over previous
//
#include <hip/hip_runtime.h>

// ---- geometry ----
#define GSZ 32
#define GP 34                    // padded (+1 halo each side)
#define GP2 (GP*GP)              // 1156
#define GP3 (GP*GP2)             // 39304
#define PX  (GP*GP3)             // 1336336 floats per padded fp32 channel
#define POFF (GP3+GP2+GP+1)      // offset of (0,0,0,0) inside padded channel
#define NPTS (1<<20)             // 32^4

// X-layout: bf16 [34][34][34][32][16]  (i,j,k padded; l=32; c padded to 16)
#define XT_FLOATS ((size_t)34*34*34*32*8)   // 10,061,824 float-equivalents

// per-pass slot layout (float units)
#define OFF_XIN ((size_t)0)
#define OFF_X2  ((size_t)PX)
#define OFF_X3  (OFF_X2 + XT_FLOATS)
#define OFF_OT  (OFF_X3 + XT_FLOATS)
#define SPASS   (OFF_OT + (size_t)NPTS)     // 22,508,560 floats = 90.0 MB

#define WSB_FLOATS 16384   // packed-B region: wsB2 27648B @0, wsB3 9216B @27648
#define NHALO 6536         // halo lines in 34^3 (any coord 0 or 33)

typedef __attribute__((ext_vector_type(8)))  short bf16x8;
typedef __attribute__((ext_vector_type(16))) float f32x16;

__device__ __forceinline__ unsigned short f2bf(float f) {
    union { float f; unsigned u; } v; v.f = f;
    unsigned r = v.u + 0x7FFFu + ((v.u >> 16) & 1u);   // RNE
    return (unsigned short)(r >> 16);
}

// ---------------------------------------------------------------
// pack W2: wsB2[g3][lane][4] u32, g3=(d1*3+d2)*3+d3; B[k=cin][n=d4*10+co]
// (writes zeros to unused slots, so no memset of the pack region needed)
// ---------------------------------------------------------------
__global__ void k_bpack2(const float* __restrict__ W2, unsigned* __restrict__ wsB) {
    int t = threadIdx.x;
    int lane = t & 63, j = t >> 6;
    int n = lane & 31, kh = lane >> 5;
    for (int g = 0; g < 27; ++g) {
        unsigned v = 0;
        for (int e = 0; e < 2; ++e) {
            int k = kh * 8 + 2 * j + e;
            unsigned short h = 0;
            if (k < 10 && n < 30) {
                int co = n % 10, d4 = n / 10;
                h = f2bf(W2[(co * 10 + k) * 81 + g * 3 + d4]);
            }
            v |= (unsigned)h << (16 * e);
        }
        wsB[(g * 64 + lane) * 4 + j] = v;
    }
}

// ---------------------------------------------------------------
// pack W3: wsB3[g9][lane][4] u32, g9=d1*3+d2; B[k=cin][n=d3*3+d4]
// ---------------------------------------------------------------
__global__ void k_bpack3(const float* __restrict__ W3, unsigned* __restrict__ wsB3) {
    int t = threadIdx.x;
    int lane = t & 63, j = t >> 6;
    int n = lane & 31, kh = lane >> 5;
    for (int g = 0; g < 9; ++g) {
        unsigned v = 0;
        for (int e = 0; e < 2; ++e) {
            int k = kh * 8 + 2 * j + e;
            unsigned short h = 0;
            if (k < 10 && n < 9) {
                int d3 = n / 3, d4 = n % 3;
                h = f2bf(W3[k * 81 + (g * 3 + d3) * 3 + d4]);
            }
            v |= (unsigned)h << (16 * e);
        }
        wsB3[(g * 64 + lane) * 4 + j] = v;
    }
}

// ---------------------------------------------------------------
// zero the halo lines (any of i,j,k in {0,33}) of X2 and X3 for each slot.
// one wave per line; 64 lanes x 16B = 1KB line. grid (1634, Gn)
// ---------------------------------------------------------------
__global__ __launch_bounds__(256) void k_zero_halo(float* __restrict__ ws) {
    int wid = blockIdx.x * 4 + (threadIdx.x >> 6);
    if (wid >= NHALO) return;
    int lane = threadIdx.x & 63;
    int i, j, k;
    if (wid < 2312) {                 // i in {0,33}
        i = (wid < 1156) ? 0 : 33;
        int r = wid % 1156; j = r / 34; k = r % 34;
    } else if (wid < 4488) {          // i interior, j in {0,33}
        int r = wid - 2312;
        i = 1 + r / 68;
        int r2 = r % 68;
        j = (r2 < 34) ? 0 : 33;
        k = r2 % 34;
    } else {                          // i,j interior, k in {0,33}
        int r = wid - 4488;
        i = 1 + r / 64;
        int r2 = r % 64;
        j = 1 + (r2 >> 1);
        k = (r2 & 1) ? 33 : 0;
    }
    size_t lidx = ((size_t)(i * 34 + j) * 34 + k) * 64 + lane;
    float* slot = ws + (size_t)blockIdx.y * SPASS;
    ((uint4*)(slot + OFF_X2))[lidx] = make_uint4(0u, 0u, 0u, 0u);
    ((uint4*)(slot + OFF_X3))[lidx] = make_uint4(0u, 0u, 0u, 0u);
}

// ---------------------------------------------------------------
// copy input (branch 0: identity, branch 1: (i,j,k,l)<-(k,l,i,j))
// ---------------------------------------------------------------
__global__ __launch_bounds__(256) void k_copy_in(const float* __restrict__ x,
                                                 float* __restrict__ ws, int p0) {
    int p = p0 + blockIdx.z;
    int b = p >> 1, br = p & 1;
    int gid = blockIdx.x * 256 + threadIdx.x;
    int l = gid & 31, k = (gid >> 5) & 31, j = (gid >> 10) & 31, i = gid >> 15;
    const float* xb = x + (size_t)b * NPTS;
    float v;
    if (br == 0) v = xb[gid];
    else         v = xb[(((k * 32 + l) * 32 + i) * 32) + j];
    float* xin = ws + (size_t)blockIdx.z * SPASS + OFF_XIN;
    xin[POFF + i * GP3 + j * GP2 + k * GP + l] = v;
}

// ---------------------------------------------------------------
// conv1: 1 -> 10, fp32 padded in, bf16 X2 out, ReLU
// ---------------------------------------------------------------
__global__ __launch_bounds__(256) void k_conv1(const float* __restrict__ W1,
                                               const float* __restrict__ B1,
                                               float* ws, int p0) {
    int z = blockIdx.z;
    int i = blockIdx.x, j = blockIdx.y;
    int t = threadIdx.x;
    int l = t & 31, k0 = t >> 5;
    const float* xin = ws + (size_t)z * SPASS + OFF_XIN;

    float acc[10][4];
#pragma unroll
    for (int co = 0; co < 10; ++co) {
        float bb = B1[co];
#pragma unroll
        for (int m = 0; m < 4; ++m) acc[co][m] = bb;
    }

    const float* base = xin + POFF + (size_t)(i - 1) * GP3 + (j - 1) * GP2
                        + (k0 - 1) * GP + (l - 1);
#pragma unroll 1
    for (int d1 = 0; d1 < 3; ++d1)
#pragma unroll 1
        for (int d2 = 0; d2 < 3; ++d2) {
            const float* bp = base + d1 * GP3 + d2 * GP2;
#pragma unroll
            for (int d3 = 0; d3 < 3; ++d3)
#pragma unroll
                for (int d4 = 0; d4 < 3; ++d4) {
                    float v[4];
#pragma unroll
                    for (int m = 0; m < 4; ++m) v[m] = bp[m * 8 * GP + d3 * GP + d4];
                    int tap = ((d1 * 3 + d2) * 3 + d3) * 3 + d4;
#pragma unroll
                    for (int co = 0; co < 10; ++co) {
                        float w = W1[co * 81 + tap];
#pragma unroll
                        for (int m = 0; m < 4; ++m) acc[co][m] = fmaf(v[m], w, acc[co][m]);
                    }
                }
        }

    unsigned short* X2 = (unsigned short*)(ws + (size_t)z * SPASS + OFF_X2);
#pragma unroll
    for (int m = 0; m < 4; ++m) {
        int k = k0 + 8 * m;
        unsigned short* dst = X2 + ((size_t)(((i + 1) * 34 + (j + 1)) * 34 + (k + 1))) * 512
                              + l * 16;
        unsigned u[5];
#pragma unroll
        for (int c = 0; c < 5; ++c) {
            unsigned short lo = f2bf(fmaxf(acc[2 * c][m], 0.f));
            unsigned short hi = f2bf(fmaxf(acc[2 * c + 1][m], 0.f));
            u[c] = (unsigned)lo | ((unsigned)hi << 16);
        }
        ((uint4*)dst)[0] = make_uint4(u[0], u[1], u[2], u[3]);
        ((uint4*)dst)[1] = make_uint4(u[4], 0u, 0u, 0u);
    }
}

// ---------------------------------------------------------------
// conv2 via MFMA 32x32x16 bf16, N=(d4,co). bf16 X3 output lines.
// B-frags read from global (27KB, L1-resident) — no LDS stage, no barrier.
// epilogue fully unrolled (rule #20: runtime D[] index -> scratch).
// ---------------------------------------------------------------
__global__ __launch_bounds__(256) void k_conv2m(const unsigned* __restrict__ wsB,
                                                const float* __restrict__ B2,
                                                float* ws) {
    __shared__ float epi[4][34 * 33];

    int t = threadIdx.x;
    int lane = t & 63, wv = t >> 6;
    int zslot = blockIdx.z >> 1, w = blockIdx.z & 1;
    int bid = blockIdx.x;
    int s = ((bid & 7) << 7) | (bid >> 3);
    int i = s >> 5, j = s & 31;
    int k0 = (w * 4 + wv) * 4;

    if (lane < 33) { epi[wv][lane] = 0.f; epi[wv][33 * 33 + lane] = 0.f; }

    int q = lane & 31, half = lane >> 5;
    float bias[8];
#pragma unroll
    for (int e = 0; e < 8; ++e) {
        int co = half * 8 + e;
        bias[e] = (co < 10) ? B2[co] : 0.f;
    }

    float* slot = ws + (size_t)zslot * SPASS;
    const unsigned short* X2 = (const unsigned short*)(slot + OFF_X2);
    const unsigned short* base0 = X2 + ((size_t)((i * 34 + j) * 34 + k0)) * 512
                                  + q * 16 + half * 8;
    const bf16x8* Bg = (const bf16x8*)wsB;

    f32x16 D[4] = {};

#pragma unroll 1
    for (int d1 = 0; d1 < 3; ++d1)
#pragma unroll 1
        for (int d2 = 0; d2 < 3; ++d2) {
            int g = d1 * 3 + d2;
            const unsigned short* pg = base0 + (size_t)(d1 * 1156 + d2 * 34) * 512;
            bf16x8 A[6];
#pragma unroll
            for (int kk = 0; kk < 6; ++kk)
                A[kk] = *(const bf16x8*)(pg + kk * 512);
            bf16x8 Bf[3];
#pragma unroll
            for (int d3 = 0; d3 < 3; ++d3)
                Bf[d3] = Bg[(g * 3 + d3) * 64 + lane];
#pragma unroll
            for (int kk = 0; kk < 6; ++kk)
#pragma unroll
                for (int m = 0; m < 4; ++m) {
                    int d3 = kk - m;
                    if (d3 >= 0 && d3 < 3)
                        D[m] = __builtin_amdgcn_mfma_f32_32x32x16_bf16(A[kk], Bf[d3], D[m], 0, 0, 0);
                }
        }

    // epilogue: shift-add along d4, bias, relu, pack bf16 X3 line, coalesced store
    float* epw = epi[wv];
    unsigned short* X3 = (unsigned short*)(slot + OFF_X3);
#pragma unroll
    for (int m = 0; m < 4; ++m) {
#pragma unroll
        for (int r = 0; r < 16; ++r) {
            int row = (r & 3) + 8 * (r >> 2) + 4 * half;   // D row = l
            epw[(row + 1) * 33 + q] = D[m][r];             // col = n
        }
        unsigned u[4];
#pragma unroll
        for (int e = 0; e < 4; ++e) {
            unsigned short h2[2];
#pragma unroll
            for (int x = 0; x < 2; ++x) {
                int co = half * 8 + 2 * e + x;
                float v = 0.f;
                if (co < 10) {
                    v = bias[2 * e + x];
#pragma unroll
                    for (int ss = 0; ss < 3; ++ss)
                        v += epw[(q + ss) * 33 + ss * 10 + co];
                    v = fmaxf(v, 0.f);
                }
                h2[x] = f2bf(v);
            }
            u[e] = (unsigned)h2[0] | ((unsigned)h2[1] << 16);
        }
        unsigned short* dst = X3 + ((size_t)(((i + 1) * 34 + (j + 1)) * 34 + (k0 + m + 1))) * 512
                              + q * 16 + half * 8;
        *(uint4*)dst = make_uint4(u[0], u[1], u[2], u[3]);
    }
}

// ---------------------------------------------------------------
// conv3 via MFMA 32x32x16 bf16, N=(d3,d4) 2D-shift packing, 10->1
// B-frags from global (9KB, L1-resident); barrier-free.
// ---------------------------------------------------------------
__global__ __launch_bounds__(256) void k_conv3m(const unsigned* __restrict__ wsB3,
                                                const float* __restrict__ B3,
                                                float* ws, float* __restrict__ out,
                                                int p0) {
    __shared__ float epi[4][6 * 34 * 9];

    int t = threadIdx.x;
    int lane = t & 63, wv = t >> 6;
    int zslot = blockIdx.z >> 1, w = blockIdx.z & 1;
    int p = p0 + zslot;
    int b = p >> 1, br = p & 1;
    int bid = blockIdx.x;
    int s = ((bid & 7) << 7) | (bid >> 3);
    int i = s >> 5, j = s & 31;
    int k0 = (w * 4 + wv) * 4;

    for (int idx = lane; idx < 6 * 9; idx += 64) {
        int rel = idx / 9, c = idx % 9;
        epi[wv][(rel * 34 + 0) * 9 + c] = 0.f;
        epi[wv][(rel * 34 + 33) * 9 + c] = 0.f;
    }

    float* slot = ws + (size_t)zslot * SPASS;
    const unsigned short* X3 = (const unsigned short*)(slot + OFF_X3);
    const unsigned short* base0 = X3 + ((size_t)((i * 34 + j) * 34 + k0)) * 512
                                  + (lane & 31) * 16 + (lane >> 5) * 8;
    const bf16x8* Bg = (const bf16x8*)wsB3;

    f32x16 D[6] = {};

#pragma unroll 1
    for (int g = 0; g < 9; ++g) {
        const unsigned short* pg = base0 + (size_t)((g / 3) * 1156 + (g % 3) * 34) * 512;
        bf16x8 Bf = Bg[g * 64 + lane];
#pragma unroll
        for (int rel = 0; rel < 6; ++rel) {
            bf16x8 A = *(const bf16x8*)(pg + rel * 512);
            D[rel] = __builtin_amdgcn_mfma_f32_32x32x16_bf16(A, Bf, D[rel], 0, 0, 0);
        }
    }

    int q = lane & 31, half = lane >> 5;
    float* epw = epi[wv];
    if (q < 9) {
#pragma unroll
        for (int rel = 0; rel < 6; ++rel)
#pragma unroll
            for (int r = 0; r < 16; ++r) {
                int row = (r & 3) + 8 * (r >> 2) + 4 * half;
                epw[(rel * 34 + row + 1) * 9 + q] = D[rel][r];
            }
    }
    // per-wave LDS: within-wave in-order LDS suffices (no barrier)
    float bb = B3[0];
    float vout[4];
#pragma unroll
    for (int m = 0; m < 4; ++m) {
        float v = bb;
#pragma unroll
        for (int d3 = 0; d3 < 3; ++d3)
#pragma unroll
            for (int d4 = 0; d4 < 3; ++d4)
                v += epw[((m + d3) * 34 + (q + d4)) * 9 + d3 * 3 + d4];
        vout[m] = fmaxf(v, 0.f);
    }

    float* dst = (br == 0) ? (out + (size_t)b * NPTS) : (slot + OFF_OT);
    if (half == 0)
#pragma unroll
        for (int m = 0; m < 4; ++m)
            dst[(size_t)i * 32768 + j * 1024 + (k0 + m) * 32 + q] = vout[m];
}

// ---------------------------------------------------------------
// out[b] (as M[p][q]) += ot[q][p]
// ---------------------------------------------------------------
__global__ __launch_bounds__(256) void k_tadd(float* __restrict__ out,
                                              const float* __restrict__ ot) {
    __shared__ float tile[32][33];
    int tx = threadIdx.x, ty = threadIdx.y;   // (32,8)
    int P0 = blockIdx.x * 32, Q0 = blockIdx.y * 32;
#pragma unroll
    for (int r = 0; r < 4; ++r)
        tile[ty + 8 * r][tx] = ot[(size_t)(Q0 + ty + 8 * r) * 1024 + P0 + tx];
    __syncthreads();
#pragma unroll
    for (int r = 0; r < 4; ++r)
        out[(size_t)(P0 + ty + 8 * r) * 1024 + Q0 + tx] += tile[tx][ty + 8 * r];
}

// ---------------------------------------------------------------
extern "C" void kernel_launch(void* const* d_in, const int* in_sizes, int n_in,
                              void* d_out, int out_size, void* d_ws, size_t ws_size,
                              hipStream_t stream) {
    const float* x  = (const float*)d_in[0];
    const float* W1 = (const float*)d_in[1];
    const float* b1 = (const float*)d_in[2];
    const float* W2 = (const float*)d_in[3];
    const float* b2 = (const float*)d_in[4];
    const float* W3 = (const float*)d_in[5];
    const float* b3 = (const float*)d_in[6];
    float* out = (float*)d_out;
    float* ws  = (float*)d_ws;
    float* slots = ws + WSB_FLOATS;
    unsigned* wsB2 = (unsigned*)ws;
    unsigned* wsB3 = (unsigned*)ws + 6912;

    size_t slot_bytes = SPASS * sizeof(float);
    int Gn = (int)((ws_size - WSB_FLOATS * 4) / slot_bytes);
    if (Gn > 4) Gn = 4;
    if (Gn < 1) Gn = 1;

    // zero only what must be zero: xin halos (memset whole xin) + X2/X3 halo lines
    for (int zs = 0; zs < Gn; ++zs)
        hipMemsetAsync(slots + (size_t)zs * SPASS + OFF_XIN, 0, PX * sizeof(float), stream);
    k_zero_halo<<<dim3((NHALO + 3) / 4, Gn), 256, 0, stream>>>(slots);

    k_bpack2<<<1, 256, 0, stream>>>(W2, wsB2);
    k_bpack3<<<1, 256, 0, stream>>>(W3, wsB3);

    for (int p0 = 0; p0 < 8; p0 += Gn) {
        int g = 8 - p0 < Gn ? 8 - p0 : Gn;
        k_copy_in<<<dim3(4096, 1, g), 256, 0, stream>>>(x, slots, p0);
        k_conv1<<<dim3(32, 32, g), 256, 0, stream>>>(W1, b1, slots, p0);
        k_conv2m<<<dim3(1024, 1, 2 * g), 256, 0, stream>>>(wsB2, b2, slots);
        k_conv3m<<<dim3(1024, 1, 2 * g), 256, 0, stream>>>(wsB3, b3, slots, out, p0);
        for (int p = p0; p < p0 + g; ++p)
            if (p & 1)
                k_tadd<<<dim3(32, 32), dim3(32, 8), 0, stream>>>(
                    out + (size_t)(p >> 1) * NPTS,
                    slots + (size_t)(p - p0) * SPASS + OFF_OT);
    }
}

// Round 6
// 680.210 us; speedup vs baseline: 3.8196x; 1.0482x over previous
//
#include <hip/hip_runtime.h>

// ---- geometry ----
#define GSZ 32
#define NPTS (1<<20)             // 32^4

// padded line tensors: [34][34][34] lines
// XB: bf16 [34][34][34][32]           (input, 64B lines)
// X2/X3: bf16 [34][34][34][32][16]    (10 ch + 6 zero-pad, 1KB lines)
#define XB_FLOATS ((size_t)34*34*34*16)     //   628,864 float-units
#define XT_FLOATS ((size_t)34*34*34*32*8)   // 10,061,824 float-units

#define OFF_XB  ((size_t)0)
#define OFF_X2  (XB_FLOATS)
#define OFF_X3  (OFF_X2 + XT_FLOATS)
#define OFF_OT  (OFF_X3 + XT_FLOATS)
#define SPASS   (OFF_OT + (size_t)NPTS)     // 21,801,088 floats = 87.2 MB

#define WSB_FLOATS 16384   // wsB2 @0 (6912 u32) | wsB3 @6912 (2304) | wsB1 @9216 (768)
#define NHALO 6536         // halo lines in 34^3 (any coord 0 or 33)

typedef __attribute__((ext_vector_type(8)))  short bf16x8;
typedef __attribute__((ext_vector_type(16))) float f32x16;

__device__ __forceinline__ unsigned short f2bf(float f) {
    union { float f; unsigned u; } v; v.f = f;
    unsigned r = v.u + 0x7FFFu + ((v.u >> 16) & 1u);   // RNE
    return (unsigned short)(r >> 16);
}

__device__ __forceinline__ void gll16(const void* g, void* l) {
    __builtin_amdgcn_global_load_lds(
        (const __attribute__((address_space(1))) unsigned*)g,
        (__attribute__((address_space(3))) unsigned*)l, 16, 0, 0);
}

// stage 18 consecutive k-lines (1KB each) of a [34][34][34][32][16] tensor
// for tap (d1,d2), k-window w*16 .. w*16+17, into LDS dstb (linear)
__device__ __forceinline__ void stage18(const unsigned short* Xbase, char* dstb,
                                        int i, int j, int d1, int d2, int w,
                                        int wv, int lane) {
    const unsigned short* srcb = Xbase
        + ((size_t)((i + d1) * 34 + (j + d2)) * 34 + w * 16) * 512 + lane * 8;
    char* d = dstb + lane * 16;
#pragma unroll
    for (int c = 0; c < 4; ++c) {
        int n = wv * 4 + c;
        gll16(srcb + (size_t)n * 512, d + n * 1024);
    }
    if (wv < 2) {
        int n = 16 + wv;
        gll16(srcb + (size_t)n * 512, d + n * 1024);
    }
}

// ---------------------------------------------------------------
// weight packs (write zeros to unused slots — no memset needed)
// ---------------------------------------------------------------
__global__ void k_bpack2(const float* __restrict__ W2, unsigned* __restrict__ wsB) {
    int t = threadIdx.x;
    int lane = t & 63, j = t >> 6;
    int n = lane & 31, kh = lane >> 5;
    for (int g = 0; g < 27; ++g) {
        unsigned v = 0;
        for (int e = 0; e < 2; ++e) {
            int k = kh * 8 + 2 * j + e;
            unsigned short h = 0;
            if (k < 10 && n < 30) {
                int co = n % 10, d4 = n / 10;
                h = f2bf(W2[(co * 10 + k) * 81 + g * 3 + d4]);
            }
            v |= (unsigned)h << (16 * e);
        }
        wsB[(g * 64 + lane) * 4 + j] = v;
    }
}

__global__ void k_bpack3(const float* __restrict__ W3, unsigned* __restrict__ wsB3) {
    int t = threadIdx.x;
    int lane = t & 63, j = t >> 6;
    int n = lane & 31, kh = lane >> 5;
    for (int g = 0; g < 9; ++g) {
        unsigned v = 0;
        for (int e = 0; e < 2; ++e) {
            int k = kh * 8 + 2 * j + e;
            unsigned short h = 0;
            if (k < 10 && n < 9) {
                int d3 = n / 3, d4 = n % 3;
                h = f2bf(W3[k * 81 + (g * 3 + d3) * 3 + d4]);
            }
            v |= (unsigned)h << (16 * e);
        }
        wsB3[(g * 64 + lane) * 4 + j] = v;
    }
}

// conv1 B: g = d3; B[kap=(d1,d2)][n=(d4,co)] = W1[co][d1,d2,d3,d4]
__global__ void k_bpack1(const float* __restrict__ W1, unsigned* __restrict__ wsB1) {
    int t = threadIdx.x;
    int lane = t & 63, jj = t >> 6;
    int n = lane & 31, kh = lane >> 5;
    for (int g = 0; g < 3; ++g) {
        unsigned v = 0;
        for (int e = 0; e < 2; ++e) {
            int kap = kh * 8 + 2 * jj + e;
            unsigned short h = 0;
            if (kap < 9 && n < 30) {
                int co = n % 10, d4 = n / 10;
                int d1 = kap / 3, d2 = kap % 3;
                h = f2bf(W1[co * 81 + ((d1 * 3 + d2) * 3 + g) * 3 + d4]);
            }
            v |= (unsigned)h << (16 * e);
        }
        wsB1[(g * 64 + lane) * 4 + jj] = v;
    }
}

// ---------------------------------------------------------------
// zero halo lines of XB / X2 / X3 for each slot
// ---------------------------------------------------------------
__global__ __launch_bounds__(256) void k_zero_halo(float* __restrict__ ws) {
    int wid = blockIdx.x * 4 + (threadIdx.x >> 6);
    if (wid >= NHALO) return;
    int lane = threadIdx.x & 63;
    int i, j, k;
    if (wid < 2312) {
        i = (wid < 1156) ? 0 : 33;
        int r = wid % 1156; j = r / 34; k = r % 34;
    } else if (wid < 4488) {
        int r = wid - 2312;
        i = 1 + r / 68;
        int r2 = r % 68;
        j = (r2 < 34) ? 0 : 33;
        k = r2 % 34;
    } else {
        int r = wid - 4488;
        i = 1 + r / 64;
        int r2 = r % 64;
        j = 1 + (r2 >> 1);
        k = (r2 & 1) ? 33 : 0;
    }
    size_t line = (size_t)(i * 34 + j) * 34 + k;
    float* slot = ws + (size_t)blockIdx.y * SPASS;
    uint4 z4 = make_uint4(0u, 0u, 0u, 0u);
    ((uint4*)(slot + OFF_X2))[line * 64 + lane] = z4;
    ((uint4*)(slot + OFF_X3))[line * 64 + lane] = z4;
    if (lane < 4) ((uint4*)(slot + OFF_XB))[line * 4 + lane] = z4;
}

// ---------------------------------------------------------------
// copy input to bf16 padded XB (branch 0: identity, 1: (i,j,k,l)<-(k,l,i,j))
// ---------------------------------------------------------------
__global__ __launch_bounds__(256) void k_copy_in(const float* __restrict__ x,
                                                 float* __restrict__ ws, int p0) {
    int p = p0 + blockIdx.z;
    int b = p >> 1, br = p & 1;
    int gid = blockIdx.x * 256 + threadIdx.x;
    int l = gid & 31, k = (gid >> 5) & 31, j = (gid >> 10) & 31, i = gid >> 15;
    const float* xb = x + (size_t)b * NPTS;
    float v;
    if (br == 0) v = xb[gid];
    else         v = xb[(((k * 32 + l) * 32 + i) * 32) + j];
    unsigned short* XB = (unsigned short*)(ws + (size_t)blockIdx.z * SPASS + OFF_XB);
    XB[((size_t)(((i + 1) * 34 + (j + 1)) * 34 + (k + 1))) * 32 + l] = f2bf(v);
}

// ---------------------------------------------------------------
// conv1 via MFMA 32x32x16: K=(d1,d2) 9-of-16, N=(d4,co), d3 folded via kk/m.
// ---------------------------------------------------------------
__global__ __launch_bounds__(256) void k_conv1m(const unsigned* __restrict__ wsB1,
                                                const float* __restrict__ B1,
                                                float* ws) {
    __shared__ float epi[4][34 * 33];
    int t = threadIdx.x, lane = t & 63, wv = t >> 6;
    int zslot = blockIdx.z >> 1, w = blockIdx.z & 1;
    int bid = blockIdx.x;
    int s = ((bid & 7) << 7) | (bid >> 3);
    int i = s >> 5, j = s & 31;
    int k0g = w * 16 + wv * 4;           // padded-k of kk=0
    int q = lane & 31, half = lane >> 5;

    float bias[8];
#pragma unroll
    for (int e = 0; e < 8; ++e) {
        int co = half * 8 + e;
        bias[e] = (co < 10) ? B1[co] : 0.f;
    }
    if (lane < 33) { epi[wv][lane] = 0.f; epi[wv][33 * 33 + lane] = 0.f; }

    float* slot = ws + (size_t)zslot * SPASS;
    const unsigned short* XB = (const unsigned short*)(slot + OFF_XB);
    const unsigned short* xb = XB + ((size_t)((i * 34 + j) * 34 + k0g)) * 32 + q;
    const bf16x8* Bg = (const bf16x8*)wsB1;

    bf16x8 A[6];
    if (half == 0) {
#pragma unroll
        for (int kk = 0; kk < 6; ++kk) {
            bf16x8 a;
#pragma unroll
            for (int e = 0; e < 8; ++e) {
                const int d1 = e / 3, d2 = e % 3;
                a[e] = (short)xb[(size_t)(d1 * 34 + d2) * 1088 + kk * 32];
            }
            A[kk] = a;
        }
    } else {
#pragma unroll
        for (int kk = 0; kk < 6; ++kk) {
            bf16x8 a = {};
            a[0] = (short)xb[(size_t)(2 * 34 + 2) * 1088 + kk * 32];
            A[kk] = a;
        }
    }
    bf16x8 Bf[3];
#pragma unroll
    for (int d3 = 0; d3 < 3; ++d3) Bf[d3] = Bg[d3 * 64 + lane];

    f32x16 D[4] = {};
#pragma unroll
    for (int kk = 0; kk < 6; ++kk)
#pragma unroll
        for (int m = 0; m < 4; ++m) {
            int d3 = kk - m;
            if (d3 >= 0 && d3 < 3)
                D[m] = __builtin_amdgcn_mfma_f32_32x32x16_bf16(A[kk], Bf[d3], D[m], 0, 0, 0);
        }

    // epilogue: d4 shift-add, bias, relu, pack X2 line
    float* epw = epi[wv];
    unsigned short* X2 = (unsigned short*)(slot + OFF_X2);
#pragma unroll
    for (int m = 0; m < 4; ++m) {
#pragma unroll
        for (int r = 0; r < 16; ++r) {
            int row = (r & 3) + 8 * (r >> 2) + 4 * half;
            epw[(row + 1) * 33 + q] = D[m][r];
        }
        unsigned u[4];
#pragma unroll
        for (int e = 0; e < 4; ++e) {
            unsigned short h2[2];
#pragma unroll
            for (int xx = 0; xx < 2; ++xx) {
                int co = half * 8 + 2 * e + xx;
                float v = 0.f;
                if (co < 10) {
                    v = bias[2 * e + xx];
#pragma unroll
                    for (int ss = 0; ss < 3; ++ss)
                        v += epw[(q + ss) * 33 + ss * 10 + co];
                    v = fmaxf(v, 0.f);
                }
                h2[xx] = f2bf(v);
            }
            u[e] = (unsigned)h2[0] | ((unsigned)h2[1] << 16);
        }
        unsigned short* dst = X2 + ((size_t)(((i + 1) * 34 + (j + 1)) * 34 + (k0g + m + 1))) * 512
                              + q * 16 + half * 8;
        *(uint4*)dst = make_uint4(u[0], u[1], u[2], u[3]);
    }
}

// ---------------------------------------------------------------
// conv2 via MFMA, LDS-staged A (18 lines dbuf via global_load_lds), B from L1.
// block = (i,j,k-half), 4 waves. 2-phase pipeline: STAGE(g+1) || compute(g).
// ---------------------------------------------------------------
__global__ __launch_bounds__(256) void k_conv2m(const unsigned* __restrict__ wsB,
                                                const float* __restrict__ B2,
                                                float* ws) {
    __shared__ __align__(16) unsigned char Ablob[2 * 18432];   // dbuf A; epi overlay after loop

    int t = threadIdx.x, lane = t & 63, wv = t >> 6;
    int zslot = blockIdx.z >> 1, w = blockIdx.z & 1;
    int bid = blockIdx.x;
    int s = ((bid & 7) << 7) | (bid >> 3);
    int i = s >> 5, j = s & 31;
    int q = lane & 31, half = lane >> 5;
    int k0l = wv * 4;                    // local k-line of this wave's first output

    float bias[8];
#pragma unroll
    for (int e = 0; e < 8; ++e) {
        int co = half * 8 + e;
        bias[e] = (co < 10) ? B2[co] : 0.f;
    }

    float* slot = ws + (size_t)zslot * SPASS;
    const unsigned short* X2 = (const unsigned short*)(slot + OFF_X2);
    const bf16x8* Bg = (const bf16x8*)wsB;

    stage18(X2, (char*)Ablob, i, j, 0, 0, w, wv, lane);
    __syncthreads();

    f32x16 D[4] = {};

#pragma unroll 1
    for (int g = 0; g < 9; ++g) {
        if (g < 8) {
            int gn = g + 1;
            stage18(X2, (char*)Ablob + ((gn & 1) ? 18432 : 0), i, j, gn / 3, gn % 3, w, wv, lane);
        }
        const char* abuf = (const char*)Ablob + ((g & 1) ? 18432 : 0);
        bf16x8 A[6];
#pragma unroll
        for (int kk = 0; kk < 6; ++kk)
            A[kk] = *(const bf16x8*)(abuf + (k0l + kk) * 1024 + q * 32 + half * 16);
        bf16x8 Bf[3];
#pragma unroll
        for (int d3 = 0; d3 < 3; ++d3)
            Bf[d3] = Bg[(g * 3 + d3) * 64 + lane];
#pragma unroll
        for (int kk = 0; kk < 6; ++kk)
#pragma unroll
            for (int m = 0; m < 4; ++m) {
                int d3 = kk - m;
                if (d3 >= 0 && d3 < 3)
                    D[m] = __builtin_amdgcn_mfma_f32_32x32x16_bf16(A[kk], Bf[d3], D[m], 0, 0, 0);
            }
        __syncthreads();   // drains stage(g+1) loads; all waves done reading abuf
    }

    // epilogue (overlays Ablob): d4 shift-add, bias, relu, pack X3 line
    float* epw = (float*)Ablob + wv * 1122;
    if (lane < 33) { epw[lane] = 0.f; epw[33 * 33 + lane] = 0.f; }
    unsigned short* X3 = (unsigned short*)(slot + OFF_X3);
    int k0g = w * 16 + wv * 4;
#pragma unroll
    for (int m = 0; m < 4; ++m) {
#pragma unroll
        for (int r = 0; r < 16; ++r) {
            int row = (r & 3) + 8 * (r >> 2) + 4 * half;
            epw[(row + 1) * 33 + q] = D[m][r];
        }
        unsigned u[4];
#pragma unroll
        for (int e = 0; e < 4; ++e) {
            unsigned short h2[2];
#pragma unroll
            for (int xx = 0; xx < 2; ++xx) {
                int co = half * 8 + 2 * e + xx;
                float v = 0.f;
                if (co < 10) {
                    v = bias[2 * e + xx];
#pragma unroll
                    for (int ss = 0; ss < 3; ++ss)
                        v += epw[(q + ss) * 33 + ss * 10 + co];
                    v = fmaxf(v, 0.f);
                }
                h2[xx] = f2bf(v);
            }
            u[e] = (unsigned)h2[0] | ((unsigned)h2[1] << 16);
        }
        unsigned short* dst = X3 + ((size_t)(((i + 1) * 34 + (j + 1)) * 34 + (k0g + m + 1))) * 512
                              + q * 16 + half * 8;
        *(uint4*)dst = make_uint4(u[0], u[1], u[2], u[3]);
    }
}

// ---------------------------------------------------------------
// conv3 via MFMA, N=(d3,d4), LDS-staged A like conv2m. 10 -> 1, ReLU.
// ---------------------------------------------------------------
__global__ __launch_bounds__(256) void k_conv3m(const unsigned* __restrict__ wsB3,
                                                const float* __restrict__ B3,
                                                float* ws, float* __restrict__ out,
                                                int p0) {
    __shared__ __align__(16) unsigned char Ablob[2 * 18432];   // dbuf A; epi overlay

    int t = threadIdx.x, lane = t & 63, wv = t >> 6;
    int zslot = blockIdx.z >> 1, w = blockIdx.z & 1;
    int p = p0 + zslot;
    int b = p >> 1, br = p & 1;
    int bid = blockIdx.x;
    int s = ((bid & 7) << 7) | (bid >> 3);
    int i = s >> 5, j = s & 31;
    int q = lane & 31, half = lane >> 5;
    int k0l = wv * 4;

    float* slot = ws + (size_t)zslot * SPASS;
    const unsigned short* X3 = (const unsigned short*)(slot + OFF_X3);
    const bf16x8* Bg = (const bf16x8*)wsB3;

    stage18(X3, (char*)Ablob, i, j, 0, 0, w, wv, lane);
    __syncthreads();

    f32x16 D[6] = {};

#pragma unroll 1
    for (int g = 0; g < 9; ++g) {
        if (g < 8) {
            int gn = g + 1;
            stage18(X3, (char*)Ablob + ((gn & 1) ? 18432 : 0), i, j, gn / 3, gn % 3, w, wv, lane);
        }
        const char* abuf = (const char*)Ablob + ((g & 1) ? 18432 : 0);
        bf16x8 Bf = Bg[g * 64 + lane];
#pragma unroll
        for (int rel = 0; rel < 6; ++rel) {
            bf16x8 A = *(const bf16x8*)(abuf + (k0l + rel) * 1024 + q * 32 + half * 16);
            D[rel] = __builtin_amdgcn_mfma_f32_32x32x16_bf16(A, Bf, D[rel], 0, 0, 0);
        }
        __syncthreads();
    }

    // epilogue (overlays Ablob): combine (d3,d4) shifts
    float* epw = (float*)Ablob + wv * 1836;
    for (int idx = lane; idx < 54; idx += 64) {
        int rel = idx / 9, c = idx % 9;
        epw[(rel * 34 + 0) * 9 + c] = 0.f;
        epw[(rel * 34 + 33) * 9 + c] = 0.f;
    }
    if (q < 9) {
#pragma unroll
        for (int rel = 0; rel < 6; ++rel)
#pragma unroll
            for (int r = 0; r < 16; ++r) {
                int row = (r & 3) + 8 * (r >> 2) + 4 * half;
                epw[(rel * 34 + row + 1) * 9 + q] = D[rel][r];
            }
    }
    float bb = B3[0];
    float vout[4];
#pragma unroll
    for (int m = 0; m < 4; ++m) {
        float v = bb;
#pragma unroll
        for (int d3 = 0; d3 < 3; ++d3)
#pragma unroll
            for (int d4 = 0; d4 < 3; ++d4)
                v += epw[((m + d3) * 34 + (q + d4)) * 9 + d3 * 3 + d4];
        vout[m] = fmaxf(v, 0.f);
    }

    int k0g = w * 16 + wv * 4;
    float* dst = (br == 0) ? (out + (size_t)b * NPTS) : (slot + OFF_OT);
    if (half == 0)
#pragma unroll
        for (int m = 0; m < 4; ++m)
            dst[(size_t)i * 32768 + j * 1024 + (k0g + m) * 32 + q] = vout[m];
}

// ---------------------------------------------------------------
// out[b] (as M[p][q]) += ot[q][p]
// ---------------------------------------------------------------
__global__ __launch_bounds__(256) void k_tadd(float* __restrict__ out,
                                              const float* __restrict__ ot) {
    __shared__ float tile[32][33];
    int tx = threadIdx.x, ty = threadIdx.y;   // (32,8)
    int P0 = blockIdx.x * 32, Q0 = blockIdx.y * 32;
#pragma unroll
    for (int r = 0; r < 4; ++r)
        tile[ty + 8 * r][tx] = ot[(size_t)(Q0 + ty + 8 * r) * 1024 + P0 + tx];
    __syncthreads();
#pragma unroll
    for (int r = 0; r < 4; ++r)
        out[(size_t)(P0 + ty + 8 * r) * 1024 + Q0 + tx] += tile[tx][ty + 8 * r];
}

// ---------------------------------------------------------------
extern "C" void kernel_launch(void* const* d_in, const int* in_sizes, int n_in,
                              void* d_out, int out_size, void* d_ws, size_t ws_size,
                              hipStream_t stream) {
    const float* x  = (const float*)d_in[0];
    const float* W1 = (const float*)d_in[1];
    const float* b1 = (const float*)d_in[2];
    const float* W2 = (const float*)d_in[3];
    const float* b2 = (const float*)d_in[4];
    const float* W3 = (const float*)d_in[5];
    const float* b3 = (const float*)d_in[6];
    float* out = (float*)d_out;
    float* ws  = (float*)d_ws;
    float* slots = ws + WSB_FLOATS;
    unsigned* wsB2 = (unsigned*)ws;
    unsigned* wsB3 = (unsigned*)ws + 6912;
    unsigned* wsB1 = (unsigned*)ws + 9216;

    size_t slot_bytes = SPASS * sizeof(float);
    int Gn = (int)((ws_size - WSB_FLOATS * 4) / slot_bytes);
    if (Gn > 4) Gn = 4;
    if (Gn < 1) Gn = 1;

    k_zero_halo<<<dim3((NHALO + 3) / 4, Gn), 256, 0, stream>>>(slots);
    k_bpack2<<<1, 256, 0, stream>>>(W2, wsB2);
    k_bpack3<<<1, 256, 0, stream>>>(W3, wsB3);
    k_bpack1<<<1, 256, 0, stream>>>(W1, wsB1);

    for (int p0 = 0; p0 < 8; p0 += Gn) {
        int g = 8 - p0 < Gn ? 8 - p0 : Gn;
        k_copy_in<<<dim3(4096, 1, g), 256, 0, stream>>>(x, slots, p0);
        k_conv1m<<<dim3(1024, 1, 2 * g), 256, 0, stream>>>(wsB1, b1, slots);
        k_conv2m<<<dim3(1024, 1, 2 * g), 256, 0, stream>>>(wsB2, b2, slots);
        k_conv3m<<<dim3(1024, 1, 2 * g), 256, 0, stream>>>(wsB3, b3, slots, out, p0);
        for (int p = p0; p < p0 + g; ++p)
            if (p & 1)
                k_tadd<<<dim3(32, 32), dim3(32, 8), 0, stream>>>(
                    out + (size_t)(p >> 1) * NPTS,
                    slots + (size_t)(p - p0) * SPASS + OFF_OT);
    }
}

// Round 7
// 651.215 us; speedup vs baseline: 3.9896x; 1.0445x over previous
//
#include <hip/hip_runtime.h>

// ---- geometry ----
#define GSZ 32
#define NPTS (1<<20)             // 32^4

// padded line tensors: [34][34][34] lines
// XB: bf16 [34][34][34][32]           (input, 64B lines)
// X2/X3: bf16 [34][34][34][32][16]    (10 ch + 6 zero-pad, 1KB lines)
#define XB_FLOATS ((size_t)34*34*34*16)     //   628,864 float-units
#define XT ((size_t)34*34*34*32*8)          // 10,061,824 float-units per tensor

// per-BATCH slot: XB | X2A | X2B | X3A | X3B   (A=identity branch, B=swapped-W branch)
#define OFF_XB  ((size_t)0)
#define OFF_X2  (XB_FLOATS)
#define BSLOT   (XB_FLOATS + 4*XT)          // 40,876,160 floats = 163.5 MB

// packed-B region (u32 units): wsB2 2x6912 @0 | wsB3 2x2304 @13824 | wsB1 2x768 @18432
#define WSB_FLOATS 20480
#define NHALO 6536         // halo lines in 34^3 (any coord 0 or 33)

typedef __attribute__((ext_vector_type(8)))  short bf16x8;
typedef __attribute__((ext_vector_type(16))) float f32x16;

__device__ __forceinline__ unsigned short f2bf(float f) {
    union { float f; unsigned u; } v; v.f = f;
    unsigned r = v.u + 0x7FFFu + ((v.u >> 16) & 1u);   // RNE
    return (unsigned short)(r >> 16);
}

// ---------------------------------------------------------------
// weight packs, both branches. branch 1 uses W'[d1,d2,d3,d4]=W[d3,d4,d1,d2].
// ---------------------------------------------------------------
__global__ void k_bpack2(const float* __restrict__ W2, unsigned* __restrict__ wsB) {
    int t = threadIdx.x;
    int lane = t & 63, j = t >> 6;
    int n = lane & 31, kh = lane >> 5;
    for (int br = 0; br < 2; ++br)
        for (int g = 0; g < 27; ++g) {
            int d1 = g / 9, d2 = (g / 3) % 3, d3 = g % 3;
            unsigned v = 0;
            for (int e = 0; e < 2; ++e) {
                int k = kh * 8 + 2 * j + e;
                unsigned short h = 0;
                if (k < 10 && n < 30) {
                    int co = n % 10, d4 = n / 10;
                    int tap = br == 0 ? ((d1 * 3 + d2) * 3 + d3) * 3 + d4
                                      : ((d3 * 3 + d4) * 3 + d1) * 3 + d2;
                    h = f2bf(W2[(co * 10 + k) * 81 + tap]);
                }
                v |= (unsigned)h << (16 * e);
            }
            wsB[((br * 27 + g) * 64 + lane) * 4 + j] = v;
        }
}

__global__ void k_bpack3(const float* __restrict__ W3, unsigned* __restrict__ wsB3) {
    int t = threadIdx.x;
    int lane = t & 63, j = t >> 6;
    int n = lane & 31, kh = lane >> 5;
    for (int br = 0; br < 2; ++br)
        for (int g = 0; g < 9; ++g) {
            int d1 = g / 3, d2 = g % 3;
            unsigned v = 0;
            for (int e = 0; e < 2; ++e) {
                int k = kh * 8 + 2 * j + e;
                unsigned short h = 0;
                if (k < 10 && n < 9) {
                    int d3 = n / 3, d4 = n % 3;
                    int tap = br == 0 ? ((d1 * 3 + d2) * 3 + d3) * 3 + d4
                                      : ((d3 * 3 + d4) * 3 + d1) * 3 + d2;
                    h = f2bf(W3[k * 81 + tap]);
                }
                v |= (unsigned)h << (16 * e);
            }
            wsB3[((br * 9 + g) * 64 + lane) * 4 + j] = v;
        }
}

// conv1 B: g = d3; B[kap=(d1,d2)][n=(d4,co)]
__global__ void k_bpack1(const float* __restrict__ W1, unsigned* __restrict__ wsB1) {
    int t = threadIdx.x;
    int lane = t & 63, jj = t >> 6;
    int n = lane & 31, kh = lane >> 5;
    for (int br = 0; br < 2; ++br)
        for (int g = 0; g < 3; ++g) {
            unsigned v = 0;
            for (int e = 0; e < 2; ++e) {
                int kap = kh * 8 + 2 * jj + e;
                unsigned short h = 0;
                if (kap < 9 && n < 30) {
                    int co = n % 10, d4 = n / 10;
                    int d1 = kap / 3, d2 = kap % 3;
                    int tap = br == 0 ? ((d1 * 3 + d2) * 3 + g) * 3 + d4
                                      : ((g * 3 + d4) * 3 + d1) * 3 + d2;
                    h = f2bf(W1[co * 81 + tap]);
                }
                v |= (unsigned)h << (16 * e);
            }
            wsB1[((br * 3 + g) * 64 + lane) * 4 + jj] = v;
        }
}

// ---------------------------------------------------------------
// zero halo lines of XB / X2A / X2B / X3A / X3B for each batch slot
// ---------------------------------------------------------------
__global__ __launch_bounds__(256) void k_zero_halo(float* __restrict__ ws) {
    int wid = blockIdx.x * 4 + (threadIdx.x >> 6);
    if (wid >= NHALO) return;
    int lane = threadIdx.x & 63;
    int i, j, k;
    if (wid < 2312) {
        i = (wid < 1156) ? 0 : 33;
        int r = wid % 1156; j = r / 34; k = r % 34;
    } else if (wid < 4488) {
        int r = wid - 2312;
        i = 1 + r / 68;
        int r2 = r % 68;
        j = (r2 < 34) ? 0 : 33;
        k = r2 % 34;
    } else {
        int r = wid - 4488;
        i = 1 + r / 64;
        int r2 = r % 64;
        j = 1 + (r2 >> 1);
        k = (r2 & 1) ? 33 : 0;
    }
    size_t line = (size_t)(i * 34 + j) * 34 + k;
    float* slot = ws + (size_t)blockIdx.y * BSLOT;
    uint4 z4 = make_uint4(0u, 0u, 0u, 0u);
#pragma unroll
    for (int tns = 0; tns < 4; ++tns)
        ((uint4*)(slot + OFF_X2 + tns * XT))[line * 64 + lane] = z4;
    if (lane < 4) ((uint4*)(slot + OFF_XB))[line * 4 + lane] = z4;
}

// ---------------------------------------------------------------
// copy input to bf16 padded XB (identity only — one per batch)
// ---------------------------------------------------------------
__global__ __launch_bounds__(256) void k_copy_in(const float* __restrict__ x,
                                                 float* __restrict__ ws, int b0) {
    int b = b0 + blockIdx.z;
    int gid = blockIdx.x * 256 + threadIdx.x;
    int l = gid & 31, k = (gid >> 5) & 31, j = (gid >> 10) & 31, i = gid >> 15;
    float v = x[(size_t)b * NPTS + gid];
    unsigned short* XB = (unsigned short*)(ws + (size_t)blockIdx.z * BSLOT + OFF_XB);
    XB[((size_t)(((i + 1) * 34 + (j + 1)) * 34 + (k + 1))) * 32 + l] = f2bf(v);
}

// ---------------------------------------------------------------
// conv1 via MFMA 32x32x16: K=(d1,d2) 9-of-16, N=(d4,co), d3 folded via kk/m.
// z = (batch<<2) | (branch<<1) | khalf
// ---------------------------------------------------------------
__global__ __launch_bounds__(256) void k_conv1m(const unsigned* __restrict__ wsB1,
                                                const float* __restrict__ B1,
                                                float* ws) {
    __shared__ float epi[4][34 * 33];
    int t = threadIdx.x, lane = t & 63, wv = t >> 6;
    int zb = blockIdx.z >> 2, br = (blockIdx.z >> 1) & 1, w = blockIdx.z & 1;
    int bid = blockIdx.x;
    int s = ((bid & 7) << 7) | (bid >> 3);
    int i = s >> 5, j = s & 31;
    int k0g = w * 16 + wv * 4;           // padded-k of kk=0
    int q = lane & 31, half = lane >> 5;

    float bias[8];
#pragma unroll
    for (int e = 0; e < 8; ++e) {
        int co = half * 8 + e;
        bias[e] = (co < 10) ? B1[co] : 0.f;
    }
    if (lane < 33) { epi[wv][lane] = 0.f; epi[wv][33 * 33 + lane] = 0.f; }

    float* slot = ws + (size_t)zb * BSLOT;
    const unsigned short* XB = (const unsigned short*)(slot + OFF_XB);
    const unsigned short* xb = XB + ((size_t)((i * 34 + j) * 34 + k0g)) * 32 + q;
    const bf16x8* Bg = (const bf16x8*)(wsB1 + br * 3 * 64 * 4);

    bf16x8 A[6];
    if (half == 0) {
#pragma unroll
        for (int kk = 0; kk < 6; ++kk) {
            bf16x8 a;
#pragma unroll
            for (int e = 0; e < 8; ++e) {
                const int d1 = e / 3, d2 = e % 3;
                a[e] = (short)xb[(size_t)(d1 * 34 + d2) * 1088 + kk * 32];
            }
            A[kk] = a;
        }
    } else {
#pragma unroll
        for (int kk = 0; kk < 6; ++kk) {
            bf16x8 a = {};
            a[0] = (short)xb[(size_t)(2 * 34 + 2) * 1088 + kk * 32];
            A[kk] = a;
        }
    }
    bf16x8 Bf[3];
#pragma unroll
    for (int d3 = 0; d3 < 3; ++d3) Bf[d3] = Bg[d3 * 64 + lane];

    f32x16 D[4] = {};
#pragma unroll
    for (int kk = 0; kk < 6; ++kk)
#pragma unroll
        for (int m = 0; m < 4; ++m) {
            int d3 = kk - m;
            if (d3 >= 0 && d3 < 3)
                D[m] = __builtin_amdgcn_mfma_f32_32x32x16_bf16(A[kk], Bf[d3], D[m], 0, 0, 0);
        }

    // epilogue: d4 shift-add, bias, relu, pack X2 line
    float* epw = epi[wv];
    unsigned short* X2 = (unsigned short*)(slot + OFF_X2 + (size_t)br * XT);
#pragma unroll
    for (int m = 0; m < 4; ++m) {
#pragma unroll
        for (int r = 0; r < 16; ++r) {
            int row = (r & 3) + 8 * (r >> 2) + 4 * half;
            epw[(row + 1) * 33 + q] = D[m][r];
        }
        unsigned u[4];
#pragma unroll
        for (int e = 0; e < 4; ++e) {
            unsigned short h2[2];
#pragma unroll
            for (int xx = 0; xx < 2; ++xx) {
                int co = half * 8 + 2 * e + xx;
                float v = 0.f;
                if (co < 10) {
                    v = bias[2 * e + xx];
#pragma unroll
                    for (int ss = 0; ss < 3; ++ss)
                        v += epw[(q + ss) * 33 + ss * 10 + co];
                    v = fmaxf(v, 0.f);
                }
                h2[xx] = f2bf(v);
            }
            u[e] = (unsigned)h2[0] | ((unsigned)h2[1] << 16);
        }
        unsigned short* dst = X2 + ((size_t)(((i + 1) * 34 + (j + 1)) * 34 + (k0g + m + 1))) * 512
                              + q * 16 + half * 8;
        *(uint4*)dst = make_uint4(u[0], u[1], u[2], u[3]);
    }
}

// ---------------------------------------------------------------
// conv2 via MFMA 32x32x16, N=(d4,co). A direct from global (L1/L2), B from L1.
// (R5-proven structure: no LDS staging, no barrier.)
// ---------------------------------------------------------------
__global__ __launch_bounds__(256) void k_conv2m(const unsigned* __restrict__ wsB,
                                                const float* __restrict__ B2,
                                                float* ws) {
    __shared__ float epi[4][34 * 33];

    int t = threadIdx.x;
    int lane = t & 63, wv = t >> 6;
    int zb = blockIdx.z >> 2, br = (blockIdx.z >> 1) & 1, w = blockIdx.z & 1;
    int bid = blockIdx.x;
    int s = ((bid & 7) << 7) | (bid >> 3);
    int i = s >> 5, j = s & 31;
    int k0 = (w * 4 + wv) * 4;

    if (lane < 33) { epi[wv][lane] = 0.f; epi[wv][33 * 33 + lane] = 0.f; }

    int q = lane & 31, half = lane >> 5;
    float bias[8];
#pragma unroll
    for (int e = 0; e < 8; ++e) {
        int co = half * 8 + e;
        bias[e] = (co < 10) ? B2[co] : 0.f;
    }

    float* slot = ws + (size_t)zb * BSLOT;
    const unsigned short* X2 = (const unsigned short*)(slot + OFF_X2 + (size_t)br * XT);
    const unsigned short* base0 = X2 + ((size_t)((i * 34 + j) * 34 + k0)) * 512
                                  + q * 16 + half * 8;
    const bf16x8* Bg = (const bf16x8*)(wsB + br * 27 * 64 * 4);

    f32x16 D[4] = {};

#pragma unroll 1
    for (int d1 = 0; d1 < 3; ++d1)
#pragma unroll 1
        for (int d2 = 0; d2 < 3; ++d2) {
            int g = d1 * 3 + d2;
            const unsigned short* pg = base0 + (size_t)(d1 * 1156 + d2 * 34) * 512;
            bf16x8 A[6];
#pragma unroll
            for (int kk = 0; kk < 6; ++kk)
                A[kk] = *(const bf16x8*)(pg + kk * 512);
            bf16x8 Bf[3];
#pragma unroll
            for (int d3 = 0; d3 < 3; ++d3)
                Bf[d3] = Bg[(g * 3 + d3) * 64 + lane];
#pragma unroll
            for (int kk = 0; kk < 6; ++kk)
#pragma unroll
                for (int m = 0; m < 4; ++m) {
                    int d3 = kk - m;
                    if (d3 >= 0 && d3 < 3)
                        D[m] = __builtin_amdgcn_mfma_f32_32x32x16_bf16(A[kk], Bf[d3], D[m], 0, 0, 0);
                }
        }

    // epilogue: shift-add along d4, bias, relu, pack bf16 X3 line
    float* epw = epi[wv];
    unsigned short* X3 = (unsigned short*)(slot + OFF_X2 + (size_t)(2 + br) * XT);
#pragma unroll
    for (int m = 0; m < 4; ++m) {
#pragma unroll
        for (int r = 0; r < 16; ++r) {
            int row = (r & 3) + 8 * (r >> 2) + 4 * half;   // D row = l
            epw[(row + 1) * 33 + q] = D[m][r];             // col = n
        }
        unsigned u[4];
#pragma unroll
        for (int e = 0; e < 4; ++e) {
            unsigned short h2[2];
#pragma unroll
            for (int xx = 0; xx < 2; ++xx) {
                int co = half * 8 + 2 * e + xx;
                float v = 0.f;
                if (co < 10) {
                    v = bias[2 * e + xx];
#pragma unroll
                    for (int ss = 0; ss < 3; ++ss)
                        v += epw[(q + ss) * 33 + ss * 10 + co];
                    v = fmaxf(v, 0.f);
                }
                h2[xx] = f2bf(v);
            }
            u[e] = (unsigned)h2[0] | ((unsigned)h2[1] << 16);
        }
        unsigned short* dst = X3 + ((size_t)(((i + 1) * 34 + (j + 1)) * 34 + (k0 + m + 1))) * 512
                              + q * 16 + half * 8;
        *(uint4*)dst = make_uint4(u[0], u[1], u[2], u[3]);
    }
}

// ---------------------------------------------------------------
// conv3 via MFMA, N=(d3,d4) 2D-shift packing, 10->1, ReLU.
// addmode=0: out = v (branch A). addmode=1: out += v (branch B, later launch).
// z = (batch<<1) | khalf
// ---------------------------------------------------------------
__global__ __launch_bounds__(256) void k_conv3m(const unsigned* __restrict__ wsB3,
                                                const float* __restrict__ B3,
                                                float* ws, float* __restrict__ out,
                                                int b0, int br) {
    __shared__ float epi[4][6 * 34 * 9];

    int t = threadIdx.x;
    int lane = t & 63, wv = t >> 6;
    int zb = blockIdx.z >> 1, w = blockIdx.z & 1;
    int b = b0 + zb;
    int bid = blockIdx.x;
    int s = ((bid & 7) << 7) | (bid >> 3);
    int i = s >> 5, j = s & 31;
    int k0 = (w * 4 + wv) * 4;

    for (int idx = lane; idx < 6 * 9; idx += 64) {
        int rel = idx / 9, c = idx % 9;
        epi[wv][(rel * 34 + 0) * 9 + c] = 0.f;
        epi[wv][(rel * 34 + 33) * 9 + c] = 0.f;
    }

    float* slot = ws + (size_t)zb * BSLOT;
    const unsigned short* X3 = (const unsigned short*)(slot + OFF_X2 + (size_t)(2 + br) * XT);
    const unsigned short* base0 = X3 + ((size_t)((i * 34 + j) * 34 + k0)) * 512
                                  + (lane & 31) * 16 + (lane >> 5) * 8;
    const bf16x8* Bg = (const bf16x8*)(wsB3 + br * 9 * 64 * 4);

    f32x16 D[6] = {};

#pragma unroll 1
    for (int g = 0; g < 9; ++g) {
        const unsigned short* pg = base0 + (size_t)((g / 3) * 1156 + (g % 3) * 34) * 512;
        bf16x8 Bf = Bg[g * 64 + lane];
#pragma unroll
        for (int rel = 0; rel < 6; ++rel) {
            bf16x8 A = *(const bf16x8*)(pg + rel * 512);
            D[rel] = __builtin_amdgcn_mfma_f32_32x32x16_bf16(A, Bf, D[rel], 0, 0, 0);
        }
    }

    int q = lane & 31, half = lane >> 5;
    float* epw = epi[wv];
    if (q < 9) {
#pragma unroll
        for (int rel = 0; rel < 6; ++rel)
#pragma unroll
            for (int r = 0; r < 16; ++r) {
                int row = (r & 3) + 8 * (r >> 2) + 4 * half;
                epw[(rel * 34 + row + 1) * 9 + q] = D[rel][r];
            }
    }
    // per-wave LDS: within-wave in-order LDS suffices (no barrier)
    float bb = B3[0];
    float vout[4];
#pragma unroll
    for (int m = 0; m < 4; ++m) {
        float v = bb;
#pragma unroll
        for (int d3 = 0; d3 < 3; ++d3)
#pragma unroll
            for (int d4 = 0; d4 < 3; ++d4)
                v += epw[((m + d3) * 34 + (q + d4)) * 9 + d3 * 3 + d4];
        vout[m] = fmaxf(v, 0.f);
    }

    float* dst = out + (size_t)b * NPTS;
    if (half == 0) {
        if (br == 0) {
#pragma unroll
            for (int m = 0; m < 4; ++m)
                dst[(size_t)i * 32768 + j * 1024 + (k0 + m) * 32 + q] = vout[m];
        } else {
#pragma unroll
            for (int m = 0; m < 4; ++m) {
                size_t o = (size_t)i * 32768 + j * 1024 + (k0 + m) * 32 + q;
                dst[o] = dst[o] + vout[m];
            }
        }
    }
}

// ---------------------------------------------------------------
extern "C" void kernel_launch(void* const* d_in, const int* in_sizes, int n_in,
                              void* d_out, int out_size, void* d_ws, size_t ws_size,
                              hipStream_t stream) {
    const float* x  = (const float*)d_in[0];
    const float* W1 = (const float*)d_in[1];
    const float* b1 = (const float*)d_in[2];
    const float* W2 = (const float*)d_in[3];
    const float* b2 = (const float*)d_in[4];
    const float* W3 = (const float*)d_in[5];
    const float* b3 = (const float*)d_in[6];
    float* out = (float*)d_out;
    float* ws  = (float*)d_ws;
    float* slots = ws + WSB_FLOATS;
    unsigned* wsB2 = (unsigned*)ws;
    unsigned* wsB3 = (unsigned*)ws + 13824;
    unsigned* wsB1 = (unsigned*)ws + 18432;

    size_t slot_bytes = BSLOT * sizeof(float);
    int GB = (int)((ws_size - WSB_FLOATS * 4) / slot_bytes);
    if (GB > 2) GB = 2;
    if (GB < 1) GB = 1;

    k_zero_halo<<<dim3((NHALO + 3) / 4, GB), 256, 0, stream>>>(slots);
    k_bpack2<<<1, 256, 0, stream>>>(W2, wsB2);
    k_bpack3<<<1, 256, 0, stream>>>(W3, wsB3);
    k_bpack1<<<1, 256, 0, stream>>>(W1, wsB1);

    for (int b0 = 0; b0 < 4; b0 += GB) {
        int gb = 4 - b0 < GB ? 4 - b0 : GB;
        k_copy_in<<<dim3(4096, 1, gb), 256, 0, stream>>>(x, slots, b0);
        k_conv1m<<<dim3(1024, 1, 4 * gb), 256, 0, stream>>>(wsB1, b1, slots);
        k_conv2m<<<dim3(1024, 1, 4 * gb), 256, 0, stream>>>(wsB2, b2, slots);
        k_conv3m<<<dim3(1024, 1, 2 * gb), 256, 0, stream>>>(wsB3, b3, slots, out, b0, 0);
        k_conv3m<<<dim3(1024, 1, 2 * gb), 256, 0, stream>>>(wsB3, b3, slots, out, b0, 1);
    }
}